// Round 2
// baseline (2347.985 us; speedup 1.0000x reference)
//
#include <hip/hip_runtime.h>
#include <hip/hip_bf16.h>

#define EPSV 1e-5

__device__ __forceinline__ float fsign(float x) {
    return (float)((x > 0.f) - (x < 0.f));
}

// ---------------- sign(weights) precompute ----------------
struct WPtrs {
    const float* src[13];
    float* dst[13];
    int n[13];
};

__global__ void sign_weights_kernel(WPtrs wp) {
    int wi = blockIdx.y;
    int n = wp.n[wi];
    const float* s = wp.src[wi];
    float* d = wp.dst[wi];
    for (int i = blockIdx.x * blockDim.x + threadIdx.x; i < n; i += gridDim.x * blockDim.x)
        d[i] = fsign(s[i]);
}

// ---------------- stage 1 (float conv -> float conv) ----------------
// x: (512, 1, 1100, 9); conv1 w(16,1,5,1) pad(2,0); conv2 w(16,16,5,1) stride(5,1)
// out p1: (512,16,220,9)
__global__ void stage1_kernel(const float* __restrict__ x, const float* __restrict__ sw1,
                              const float* __restrict__ sw2, float* __restrict__ p1) {
    int ho = blockIdx.x;   // 0..219
    int n  = blockIdx.y;   // 0..511
    __shared__ float xs[9][9];
    __shared__ float a1[16][5][9];
    int t = threadIdx.x;
    if (t < 81) {
        int r = t / 9, w = t % 9;
        int h = 5 * ho - 2 + r;
        xs[r][w] = (h >= 0 && h < 1100) ? x[(n * 1100 + h) * 9 + w] : 0.f;
    }
    __syncthreads();
    for (int idx = t; idx < 720; idx += 256) {
        int c = idx / 45, rem = idx % 45, i = rem / 9, w = rem % 9;
        float s = 0.f;
#pragma unroll
        for (int kh = 0; kh < 5; ++kh) s += sw1[c * 5 + kh] * xs[i + kh][w];
        a1[c][i][w] = s;
    }
    __syncthreads();
    if (t < 144) {
        int co = t / 9, w = t % 9;
        double s = 0.0;
        for (int ci = 0; ci < 16; ++ci)
#pragma unroll
            for (int kh = 0; kh < 5; ++kh)
                s += (double)(sw2[(co * 16 + ci) * 5 + kh] * a1[ci][kh][w]);
        p1[((n * 16 + co) * 220 + ho) * 9 + w] = (float)s;
    }
}

// ---------------- BN stats: deterministic two-stage ----------------
// layout NCHW: x[(n*C+c)*HW + j]; per-channel sum/sumsq in double
__global__ void stats_partial(const float* __restrict__ x, int C, int N, int HW,
                              int S, double* __restrict__ part) {
    int c = blockIdx.x, s = blockIdx.y;
    long total = (long)N * HW;
    long lo = total * s / S, hi = total * (s + 1) / S;
    double sum = 0, sq = 0;
    for (long i = lo + threadIdx.x; i < hi; i += blockDim.x) {
        int n = (int)(i / HW), j = (int)(i % HW);
        float v = x[((long)(n * C + c)) * HW + j];
        sum += v;
        sq += (double)v * v;
    }
    __shared__ double ls[256], lq[256];
    ls[threadIdx.x] = sum;
    lq[threadIdx.x] = sq;
    __syncthreads();
    for (int off = 128; off > 0; off >>= 1) {
        if ((int)threadIdx.x < off) {
            ls[threadIdx.x] += ls[threadIdx.x + off];
            lq[threadIdx.x] += lq[threadIdx.x + off];
        }
        __syncthreads();
    }
    if (threadIdx.x == 0) {
        part[(c * S + s) * 2] = ls[0];
        part[(c * S + s) * 2 + 1] = lq[0];
    }
}

__global__ void stats_final(const double* __restrict__ part, int C, int S, long count,
                            float* __restrict__ mean, float* __restrict__ rstd) {
    int c = blockIdx.x * blockDim.x + threadIdx.x;
    if (c >= C) return;
    double s = 0, q = 0;
    for (int i = 0; i < S; ++i) {
        s += part[(c * S + i) * 2];
        q += part[(c * S + i) * 2 + 1];
    }
    double m = s / (double)count;
    double v = q / (double)count - m * m;
    mean[c] = (float)m;
    rstd[c] = (float)(1.0 / sqrt(v + EPSV));
}

// ---------------- stage 2 ----------------
// in p1 (512,16,220,9) -> bn1-prelu-sign -> conv3 (32,16,5,1) pad(2,0) -> sign
// -> conv4 (32,32,5,1) stride(5,1) -> p2 (512,32,44,9)
__global__ void stage2_kernel(const float* __restrict__ p1, const float* __restrict__ mean,
                              const float* __restrict__ rstd, const float* __restrict__ g,
                              const float* __restrict__ b, const float* __restrict__ ap,
                              const float* __restrict__ sw3, const float* __restrict__ sw4,
                              float* __restrict__ p2) {
    int ho = blockIdx.x;  // 0..43
    int n = blockIdx.y;
    float a = ap[0];
    __shared__ float si[16][9][9];
    __shared__ float a2[32][5][9];
    int t = threadIdx.x;
    for (int idx = t; idx < 1296; idx += 256) {
        int c = idx / 81, r = (idx % 81) / 9, w = idx % 9;
        int h = 5 * ho - 2 + r;
        float sv = 0.f;
        if (h >= 0 && h < 220) {
            float v = p1[((n * 16 + c) * 220 + h) * 9 + w];
            float bnv = (v - mean[c]) * rstd[c] * g[c] + b[c];
            float pr = bnv < 0.f ? a * bnv : bnv;
            sv = fsign(pr);
        }
        si[c][r][w] = sv;
    }
    __syncthreads();
    for (int idx = t; idx < 1440; idx += 256) {
        int co = idx / 45, i = (idx % 45) / 9, w = idx % 9;
        float s = 0.f;
        for (int ci = 0; ci < 16; ++ci)
#pragma unroll
            for (int kh = 0; kh < 5; ++kh)
                s += sw3[(co * 16 + ci) * 5 + kh] * si[ci][i + kh][w];
        a2[co][i][w] = fsign(s);
    }
    __syncthreads();
    for (int idx = t; idx < 288; idx += 256) {
        int co = idx / 9, w = idx % 9;
        float s = 0.f;
        for (int ci = 0; ci < 32; ++ci)
#pragma unroll
            for (int kh = 0; kh < 5; ++kh)
                s += sw4[(co * 32 + ci) * 5 + kh] * a2[ci][kh][w];
        p2[((n * 32 + co) * 44 + ho) * 9 + w] = s;
    }
}

// ---------------- stage 3 ----------------
// in p2 (512,32,44,9) -> bn2-prelu-sign -> conv5 (64,32,11,1) pad(5,0) -> sign
// -> conv6 (64,64,11,1) stride(11,1) -> p3 (512,64,4,9)
__global__ void stage3_kernel(const float* __restrict__ p2, const float* __restrict__ mean,
                              const float* __restrict__ rstd, const float* __restrict__ g,
                              const float* __restrict__ b, const float* __restrict__ ap,
                              const float* __restrict__ sw5, const float* __restrict__ sw6,
                              float* __restrict__ p3) {
    int ho = blockIdx.x;  // 0..3
    int n = blockIdx.y;
    float a = ap[0];
    __shared__ float si[32][21][9];  // 6048
    __shared__ float a3[64][11][9];  // 6336
    int t = threadIdx.x;
    for (int idx = t; idx < 6048; idx += 256) {
        int c = idx / 189, r = (idx % 189) / 9, w = idx % 9;
        int h = 11 * ho - 5 + r;
        float sv = 0.f;
        if (h >= 0 && h < 44) {
            float v = p2[((n * 32 + c) * 44 + h) * 9 + w];
            float bnv = (v - mean[c]) * rstd[c] * g[c] + b[c];
            float pr = bnv < 0.f ? a * bnv : bnv;
            sv = fsign(pr);
        }
        si[c][r][w] = sv;
    }
    __syncthreads();
    for (int idx = t; idx < 6336; idx += 256) {
        int co = idx / 99, i = (idx % 99) / 9, w = idx % 9;
        float s = 0.f;
        for (int ci = 0; ci < 32; ++ci)
#pragma unroll
            for (int kh = 0; kh < 11; ++kh)
                s += sw5[(co * 32 + ci) * 11 + kh] * si[ci][i + kh][w];
        a3[co][i][w] = fsign(s);
    }
    __syncthreads();
    for (int idx = t; idx < 576; idx += 256) {
        int co = idx / 9, w = idx % 9;
        float s = 0.f;
        for (int ci = 0; ci < 64; ++ci)
#pragma unroll
            for (int kh = 0; kh < 11; ++kh)
                s += sw6[(co * 64 + ci) * 11 + kh] * a3[ci][kh][w];
        p3[((n * 64 + co) * 4 + ho) * 9 + w] = s;
    }
}

// ---------------- stage 4 ----------------
// in p3 (512,64,4,9) -> bn3-prelu-sign -> conv7 (128,64,1,3) pad(0,1) -> sign
// -> conv8 (128,128,1,3) stride(1,3) -> p4 (512,128,4,3)
__global__ void stage4_kernel(const float* __restrict__ p3, const float* __restrict__ mean,
                              const float* __restrict__ rstd, const float* __restrict__ g,
                              const float* __restrict__ b, const float* __restrict__ ap,
                              const float* __restrict__ sw7, const float* __restrict__ sw8,
                              float* __restrict__ p4) {
    int n = blockIdx.x;
    float a = ap[0];
    __shared__ float si[64][4][9];   // 2304
    __shared__ float a4[128][4][9];  // 4608
    int t = threadIdx.x;
    for (int idx = t; idx < 2304; idx += 256) {
        int c = idx / 36, h = (idx % 36) / 9, w = idx % 9;
        float v = p3[((n * 64 + c) * 4 + h) * 9 + w];
        float bnv = (v - mean[c]) * rstd[c] * g[c] + b[c];
        float pr = bnv < 0.f ? a * bnv : bnv;
        si[c][h][w] = fsign(pr);
    }
    __syncthreads();
    for (int idx = t; idx < 4608; idx += 256) {
        int co = idx / 36, h = (idx % 36) / 9, w = idx % 9;
        float s = 0.f;
        for (int ci = 0; ci < 64; ++ci)
#pragma unroll
            for (int kw = 0; kw < 3; ++kw) {
                int wl = w + kw - 1;
                if (wl >= 0 && wl < 9) s += sw7[(co * 64 + ci) * 3 + kw] * si[ci][h][wl];
            }
        a4[co][h][w] = fsign(s);
    }
    __syncthreads();
    for (int idx = t; idx < 1536; idx += 256) {
        int co = idx / 12, h = (idx % 12) / 3, wo = idx % 3;
        float s = 0.f;
        for (int ci = 0; ci < 128; ++ci)
#pragma unroll
            for (int kw = 0; kw < 3; ++kw)
                s += sw8[(co * 128 + ci) * 3 + kw] * a4[ci][h][3 * wo + kw];
        p4[((n * 128 + co) * 4 + h) * 3 + wo] = s;
    }
}

// ---------------- stage 5 ----------------
// in p4 (512,128,4,3) -> bn4-prelu-sign -> conv9 (256,128,1,3) pad(0,1) -> sign
// -> conv10 (256,256,1,3) stride(1,3) -> p5 (512,256,4,1) stored flat (n,1024)
__global__ void stage5_kernel(const float* __restrict__ p4, const float* __restrict__ mean,
                              const float* __restrict__ rstd, const float* __restrict__ g,
                              const float* __restrict__ b, const float* __restrict__ ap,
                              const float* __restrict__ sw9, const float* __restrict__ sw10,
                              float* __restrict__ p5) {
    int n = blockIdx.x;
    float a = ap[0];
    __shared__ float si[128][4][3];  // 1536
    __shared__ float a5[256][4][3];  // 3072
    int t = threadIdx.x;
    for (int idx = t; idx < 1536; idx += 256) {
        int c = idx / 12, h = (idx % 12) / 3, w = idx % 3;
        float v = p4[((n * 128 + c) * 4 + h) * 3 + w];
        float bnv = (v - mean[c]) * rstd[c] * g[c] + b[c];
        float pr = bnv < 0.f ? a * bnv : bnv;
        si[c][h][w] = fsign(pr);
    }
    __syncthreads();
    for (int idx = t; idx < 3072; idx += 256) {
        int co = idx / 12, h = (idx % 12) / 3, w = idx % 3;
        float s = 0.f;
        for (int ci = 0; ci < 128; ++ci)
#pragma unroll
            for (int kw = 0; kw < 3; ++kw) {
                int wl = w + kw - 1;
                if (wl >= 0 && wl < 3) s += sw9[(co * 128 + ci) * 3 + kw] * si[ci][h][wl];
            }
        a5[co][h][w] = fsign(s);
    }
    __syncthreads();
    for (int idx = t; idx < 1024; idx += 256) {
        int co = idx / 4, h = idx % 4;
        float s = 0.f;
        for (int ci = 0; ci < 256; ++ci)
#pragma unroll
            for (int kw = 0; kw < 3; ++kw)
                s += sw10[(co * 256 + ci) * 3 + kw] * a5[ci][h][kw];
        p5[n * 1024 + co * 4 + h] = s;  // flatten (c,h,w=1) -> c*4+h
    }
}

// ---------------- fc1: prelu(bn2d(p5)) @ sign(fc1).T ----------------
__global__ void fc1_kernel(const float* __restrict__ p5, const float* __restrict__ mean,
                           const float* __restrict__ rstd, const float* __restrict__ g,
                           const float* __restrict__ b, const float* __restrict__ ap,
                           const float* __restrict__ sfc1, float* __restrict__ h1) {
    int n = blockIdx.x;
    float a = ap[0];
    __shared__ float hv[1024];
    int t = threadIdx.x;
    for (int idx = t; idx < 1024; idx += 256) {
        int c = idx >> 2;
        float v = p5[n * 1024 + idx];
        float bnv = (v - mean[c]) * rstd[c] * g[c] + b[c];
        hv[idx] = bnv < 0.f ? a * bnv : bnv;
    }
    __syncthreads();
    int j = t;  // 256 outputs
    double s = 0.0;
    for (int k = 0; k < 1024; ++k) s += (double)(hv[k] * sfc1[j * 1024 + k]);
    h1[n * 256 + j] = (float)s;
}

// ---------------- fc2: sign(prelu(bn1d(h1))) @ sign(fc2).T ----------------
__global__ void fc2_kernel(const float* __restrict__ h1, const float* __restrict__ mean,
                           const float* __restrict__ rstd, const float* __restrict__ g,
                           const float* __restrict__ b, const float* __restrict__ ap,
                           const float* __restrict__ sfc2, float* __restrict__ h2) {
    int n = blockIdx.x;
    float a = ap[0];
    __shared__ float sv[256];
    int t = threadIdx.x;
    if (t < 256) {
        float v = h1[n * 256 + t];
        float bnv = (v - mean[t]) * rstd[t] * g[t] + b[t];
        float pr = bnv < 0.f ? a * bnv : bnv;
        sv[t] = fsign(pr);
    }
    __syncthreads();
    if (t < 64) {
        float s = 0.f;
        for (int k = 0; k < 256; ++k) s += sv[k] * sfc2[t * 256 + k];
        h2[n * 64 + t] = s;
    }
}

// ---------------- fc3: sign(prelu(bn1d(h2))) @ sign(fc3).T ----------------
__global__ void fc3_kernel(const float* __restrict__ h2, const float* __restrict__ mean,
                           const float* __restrict__ rstd, const float* __restrict__ g,
                           const float* __restrict__ b, const float* __restrict__ ap,
                           const float* __restrict__ sfc3, float* __restrict__ out) {
    int n = blockIdx.x;
    float a = ap[0];
    __shared__ float sv[64];
    int t = threadIdx.x;
    if (t < 64) {
        float v = h2[n * 64 + t];
        float bnv = (v - mean[t]) * rstd[t] * g[t] + b[t];
        float pr = bnv < 0.f ? a * bnv : bnv;
        sv[t] = fsign(pr);
    }
    __syncthreads();
    if (t < 2) {
        float s = 0.f;
        for (int k = 0; k < 64; ++k) s += sv[k] * sfc3[t * 64 + k];
        out[n * 2 + t] = s;
    }
}

extern "C" void kernel_launch(void* const* d_in, const int* in_sizes, int n_in,
                              void* d_out, int out_size, void* d_ws, size_t ws_size,
                              hipStream_t stream) {
    const float* x = (const float*)d_in[0];
    // d_in dict order: 0:x, 1-10:w1..w10, then per stage i (1..5):
    //   g_i = 11+3(i-1), b_i = 12+3(i-1), a_i = 13+3(i-1)
    // 26:fc1, 27:fc2, 28:fc3, 29:g6, 30:b6, 31:g7, 32:b7, 33:a6, 34:a7
    const float* G[8] = {nullptr, (const float*)d_in[11], (const float*)d_in[14],
                         (const float*)d_in[17], (const float*)d_in[20], (const float*)d_in[23],
                         (const float*)d_in[29], (const float*)d_in[31]};
    const float* B[8] = {nullptr, (const float*)d_in[12], (const float*)d_in[15],
                         (const float*)d_in[18], (const float*)d_in[21], (const float*)d_in[24],
                         (const float*)d_in[30], (const float*)d_in[32]};
    const float* A[8] = {nullptr, (const float*)d_in[13], (const float*)d_in[16],
                         (const float*)d_in[19], (const float*)d_in[22], (const float*)d_in[25],
                         (const float*)d_in[33], (const float*)d_in[34]};

    float* ws = (float*)d_ws;
    // signed-weight sizes
    const int wsz[13] = {80, 1280, 2560, 5120, 22528, 45056, 24576, 49152, 98304, 196608,
                         262144, 16384, 128};
    size_t off = 0;
    size_t woff[13];
    for (int i = 0; i < 13; ++i) { woff[i] = off; off += (size_t)wsz[i]; }
    float* sw1 = ws + woff[0];  float* sw2 = ws + woff[1];  float* sw3 = ws + woff[2];
    float* sw4 = ws + woff[3];  float* sw5 = ws + woff[4];  float* sw6 = ws + woff[5];
    float* sw7 = ws + woff[6];  float* sw8 = ws + woff[7];  float* sw9 = ws + woff[8];
    float* sw10 = ws + woff[9]; float* sfc1 = ws + woff[10]; float* sfc2 = ws + woff[11];
    float* sfc3 = ws + woff[12];

    float* p1 = ws + off; off += 16220160;   // 512*16*220*9
    float* p2 = ws + off; off += 6488064;    // 512*32*44*9
    float* p3 = ws + off; off += 1179648;    // 512*64*4*9
    float* p4 = ws + off; off += 786432;     // 512*128*4*3
    float* p5 = ws + off; off += 524288;     // 512*1024
    float* h1 = ws + off; off += 131072;     // 512*256
    float* h2 = ws + off; off += 32768;      // 512*64
    float* mean1 = ws + off; off += 16;  float* rstd1 = ws + off; off += 16;
    float* mean2 = ws + off; off += 32;  float* rstd2 = ws + off; off += 32;
    float* mean3 = ws + off; off += 64;  float* rstd3 = ws + off; off += 64;
    float* mean4 = ws + off; off += 128; float* rstd4 = ws + off; off += 128;
    float* mean5 = ws + off; off += 256; float* rstd5 = ws + off; off += 256;
    float* mean6 = ws + off; off += 256; float* rstd6 = ws + off; off += 256;
    float* mean7 = ws + off; off += 64;  float* rstd7 = ws + off; off += 64;
    if (off & 1) off += 1;  // 8B-align for doubles
    double* part = (double*)(ws + off); off += 2 * 16384;

    // 1. sign all weights
    WPtrs wp;
    const int wsrc_idx[13] = {1, 2, 3, 4, 5, 6, 7, 8, 9, 10, 26, 27, 28};
    for (int i = 0; i < 13; ++i) {
        wp.src[i] = (const float*)d_in[wsrc_idx[i]];
        wp.dst[i] = ws + woff[i];
        wp.n[i] = wsz[i];
    }
    hipLaunchKernelGGL(sign_weights_kernel, dim3(64, 13), dim3(256), 0, stream, wp);

    // 2. stage1
    hipLaunchKernelGGL(stage1_kernel, dim3(220, 512), dim3(256), 0, stream, x, sw1, sw2, p1);
    hipLaunchKernelGGL(stats_partial, dim3(16, 64), dim3(256), 0, stream, p1, 16, 512, 1980, 64, part);
    hipLaunchKernelGGL(stats_final, dim3(1), dim3(256), 0, stream, part, 16, 64, (long)512 * 1980, mean1, rstd1);

    // 3. stage2
    hipLaunchKernelGGL(stage2_kernel, dim3(44, 512), dim3(256), 0, stream, p1, mean1, rstd1,
                       G[1], B[1], A[1], sw3, sw4, p2);
    hipLaunchKernelGGL(stats_partial, dim3(32, 64), dim3(256), 0, stream, p2, 32, 512, 396, 64, part);
    hipLaunchKernelGGL(stats_final, dim3(1), dim3(256), 0, stream, part, 32, 64, (long)512 * 396, mean2, rstd2);

    // 4. stage3
    hipLaunchKernelGGL(stage3_kernel, dim3(4, 512), dim3(256), 0, stream, p2, mean2, rstd2,
                       G[2], B[2], A[2], sw5, sw6, p3);
    hipLaunchKernelGGL(stats_partial, dim3(64, 16), dim3(256), 0, stream, p3, 64, 512, 36, 16, part);
    hipLaunchKernelGGL(stats_final, dim3(1), dim3(256), 0, stream, part, 64, 16, (long)512 * 36, mean3, rstd3);

    // 5. stage4
    hipLaunchKernelGGL(stage4_kernel, dim3(512), dim3(256), 0, stream, p3, mean3, rstd3,
                       G[3], B[3], A[3], sw7, sw8, p4);
    hipLaunchKernelGGL(stats_partial, dim3(128, 16), dim3(256), 0, stream, p4, 128, 512, 12, 16, part);
    hipLaunchKernelGGL(stats_final, dim3(1), dim3(256), 0, stream, part, 128, 16, (long)512 * 12, mean4, rstd4);

    // 6. stage5
    hipLaunchKernelGGL(stage5_kernel, dim3(512), dim3(256), 0, stream, p4, mean4, rstd4,
                       G[4], B[4], A[4], sw9, sw10, p5);
    hipLaunchKernelGGL(stats_partial, dim3(256, 8), dim3(256), 0, stream, p5, 256, 512, 4, 8, part);
    hipLaunchKernelGGL(stats_final, dim3(1), dim3(256), 0, stream, part, 256, 8, (long)512 * 4, mean5, rstd5);

    // 7. fc1
    hipLaunchKernelGGL(fc1_kernel, dim3(512), dim3(256), 0, stream, p5, mean5, rstd5,
                       G[5], B[5], A[5], sfc1, h1);
    hipLaunchKernelGGL(stats_partial, dim3(256, 1), dim3(256), 0, stream, h1, 256, 512, 1, 1, part);
    hipLaunchKernelGGL(stats_final, dim3(1), dim3(256), 0, stream, part, 256, 1, (long)512, mean6, rstd6);

    // 8. fc2
    hipLaunchKernelGGL(fc2_kernel, dim3(512), dim3(256), 0, stream, h1, mean6, rstd6,
                       G[6], B[6], A[6], sfc2, h2);
    hipLaunchKernelGGL(stats_partial, dim3(64, 1), dim3(256), 0, stream, h2, 64, 512, 1, 1, part);
    hipLaunchKernelGGL(stats_final, dim3(1), dim3(64), 0, stream, part, 64, 1, (long)512, mean7, rstd7);

    // 9. fc3 -> d_out
    hipLaunchKernelGGL(fc3_kernel, dim3(512), dim3(256), 0, stream, h2, mean7, rstd7,
                       G[7], B[7], A[7], sfc3, (float*)d_out);
}

// Round 3
// 765.018 us; speedup vs baseline: 3.0692x; 3.0692x over previous
//
#include <hip/hip_runtime.h>
#include <hip/hip_bf16.h>

#define EPSV 1e-5

__device__ __forceinline__ float fsign(float x) {
    return (float)((x > 0.f) - (x < 0.f));
}

// ---------------- sign(weights) for float-path layers (w1, w2, fc1, fc2, fc3) ----------------
struct WPtrs {
    const float* src[5];
    float* dst[5];
    int n[5];
};

__global__ void sign_weights_kernel(WPtrs wp) {
    int wi = blockIdx.y;
    int n = wp.n[wi];
    const float* s = wp.src[wi];
    float* d = wp.dst[wi];
    for (int i = blockIdx.x * blockDim.x + threadIdx.x; i < n; i += gridDim.x * blockDim.x)
        d[i] = fsign(s[i]);
}

// ---------------- pack conv weights (w3..w10) along Cin into bit words ----------------
// layout: dnz[(co*K + k)*nw + wi], bit j = ci = wi*32+j;  nz = (w!=0), sg = (w<0)
struct PW { const float* src; unsigned* dnz; unsigned* dsg; int cout, cin, k, nw; };
struct PWall { PW l[8]; };

__global__ void pack_weights_kernel(PWall pa) {
    PW p = pa.l[blockIdx.y];
    int total = p.cout * p.k * p.nw;
    for (int u = blockIdx.x * blockDim.x + threadIdx.x; u < total; u += gridDim.x * blockDim.x) {
        int co = u / (p.k * p.nw);
        int rem = u % (p.k * p.nw);
        int kk = rem / p.nw, wi = rem % p.nw;
        unsigned nz = 0, sg = 0;
        for (int j = 0; j < 32; ++j) {
            int ci = wi * 32 + j;
            if (ci < p.cin) {
                float v = p.src[(co * p.cin + ci) * p.k + kk];
                if (v != 0.f) nz |= 1u << j;
                if (v < 0.f) sg |= 1u << j;
            }
        }
        p.dnz[u] = nz;
        p.dsg[u] = sg;
    }
}

// ---------------- stage 1 (float conv -> float conv), bit-exact vs round-2 version ----------------
// x: (512,1,1100,9); conv1 w(16,1,5,1) pad(2,0) fp32; conv2 w(16,16,5,1) stride(5,1) fp64-accum
// grid (22, 512): block = (10 output rows, n). out p1: (512,16,220,9)
__global__ void stage1_kernel(const float* __restrict__ x, const float* __restrict__ sw1,
                              const float* __restrict__ sw2, float* __restrict__ p1) {
    int n = blockIdx.y;
    int ho0 = blockIdx.x * 10;
    __shared__ float xs[54 * 9];       // x rows 5*ho0-2 .. 5*ho0+51
    __shared__ float a1L[50 * 145];    // conv1 rows 5*ho0 .. 5*ho0+49; [rr][ci*9+w], padded stride 145
    int t = threadIdx.x;
    int hbase = 5 * ho0 - 2;
    for (int i = t; i < 54 * 9; i += 256) {
        int r = i / 9, w = i % 9, h = hbase + r;
        xs[i] = (h >= 0 && h < 1100) ? x[(n * 1100 + h) * 9 + w] : 0.f;
    }
    __syncthreads();
    for (int i = t; i < 7200; i += 256) {
        int rr = i / 144, rem = i % 144, ci = rem / 9, w = rem % 9;
        float s = 0.f;
#pragma unroll
        for (int k5 = 0; k5 < 5; ++k5) s += sw1[ci * 5 + k5] * xs[(rr + k5) * 9 + w];
        a1L[rr * 145 + rem] = s;
    }
    __syncthreads();
    for (int o = t; o < 1440; o += 256) {
        int co = o / 90, rem = o % 90, hoL = rem / 9, w = rem % 9;
        double s = 0.0;
        for (int ci = 0; ci < 16; ++ci)
#pragma unroll
            for (int kh = 0; kh < 5; ++kh)
                s += (double)(sw2[(co * 16 + ci) * 5 + kh] * a1L[(hoL * 5 + kh) * 145 + ci * 9 + w]);
        p1[((n * 16 + co) * 220 + (ho0 + hoL)) * 9 + w] = (float)s;
    }
}

// ---------------- BN stats: deterministic two-stage (unchanged) ----------------
__global__ void stats_partial(const float* __restrict__ x, int C, int N, int HW,
                              int S, double* __restrict__ part) {
    int c = blockIdx.x, s = blockIdx.y;
    long total = (long)N * HW;
    long lo = total * s / S, hi = total * (s + 1) / S;
    double sum = 0, sq = 0;
    for (long i = lo + threadIdx.x; i < hi; i += blockDim.x) {
        int n = (int)(i / HW), j = (int)(i % HW);
        float v = x[((long)(n * C + c)) * HW + j];
        sum += v;
        sq += (double)v * v;
    }
    __shared__ double ls[256], lq[256];
    ls[threadIdx.x] = sum;
    lq[threadIdx.x] = sq;
    __syncthreads();
    for (int off = 128; off > 0; off >>= 1) {
        if ((int)threadIdx.x < off) {
            ls[threadIdx.x] += ls[threadIdx.x + off];
            lq[threadIdx.x] += lq[threadIdx.x + off];
        }
        __syncthreads();
    }
    if (threadIdx.x == 0) {
        part[(c * S + s) * 2] = ls[0];
        part[(c * S + s) * 2 + 1] = lq[0];
    }
}

__global__ void stats_final(const double* __restrict__ part, int C, int S, long count,
                            float* __restrict__ mean, float* __restrict__ rstd) {
    int c = blockIdx.x * blockDim.x + threadIdx.x;
    if (c >= C) return;
    double s = 0, q = 0;
    for (int i = 0; i < S; ++i) {
        s += part[(c * S + i) * 2];
        q += part[(c * S + i) * 2 + 1];
    }
    double m = s / (double)count;
    double v = q / (double)count - m * m;
    mean[c] = (float)m;
    rstd[c] = (float)(1.0 / sqrt(v + EPSV));
}

// ---------------- stage 2: bitpacked. p1 -> bn-sign pack (16ch) -> conv3 -> conv4 -> p2 ----------------
// grid(512), block 256. p2: (512,32,44,9)
__global__ void stage2_kernel(const float* __restrict__ p1, const float* __restrict__ mean,
    const float* __restrict__ rstd, const float* __restrict__ g, const float* __restrict__ b,
    const float* __restrict__ ap, const unsigned* __restrict__ w3n, const unsigned* __restrict__ w3s,
    const unsigned* __restrict__ w4n, const unsigned* __restrict__ w4s, float* __restrict__ p2) {
    int n = blockIdx.x;
    float a = ap[0];
    __shared__ unsigned qn[1980], qs[1980];
    __shared__ unsigned an[1980], ag[1980];
    int t = threadIdx.x;
    for (int p = t; p < 1980; p += 256) {
        unsigned nz = 0, sg = 0;
        for (int ci = 0; ci < 16; ++ci) {
            float v = p1[(n * 16 + ci) * 1980 + p];
            float bnv = (v - mean[ci]) * rstd[ci] * g[ci] + b[ci];
            float pr = bnv < 0.f ? a * bnv : bnv;
            if (pr != 0.f) { nz |= 1u << ci; if (pr < 0.f) sg |= 1u << ci; }
        }
        qn[p] = nz; qs[p] = sg;
    }
    __syncthreads();
    // conv3: 16->32 ch, kh=5, pad 2 (rows 0..219)
    for (int p = t; p < 1980; p += 256) {
        int j = p / 9, w = p % 9;
        unsigned xn[5], xg[5];
#pragma unroll
        for (int kh = 0; kh < 5; ++kh) {
            int r = j - 2 + kh;
            bool v = (r >= 0 && r < 220);
            xn[kh] = v ? qn[r * 9 + w] : 0u;
            xg[kh] = v ? qs[r * 9 + w] : 0u;
        }
        unsigned onz = 0, osg = 0;
        for (int co = 0; co < 32; ++co) {
            int cnt = 0, neg = 0;
#pragma unroll
            for (int kh = 0; kh < 5; ++kh) {
                unsigned both = xn[kh] & w3n[co * 5 + kh];
                cnt += __popc(both);
                neg += __popc((xg[kh] ^ w3s[co * 5 + kh]) & both);
            }
            int s = cnt - 2 * neg;
            if (s != 0) { onz |= 1u << co; if (s < 0) osg |= 1u << co; }
        }
        an[p] = onz; ag[p] = osg;
    }
    __syncthreads();
    // conv4: 32->32 ch, kh=5, stride 5 -> 44 rows
    for (int o = t; o < 12672; o += 256) {
        int co = o / 396, rem = o % 396, ho = rem / 9, w = rem % 9;
        int cnt = 0, neg = 0;
#pragma unroll
        for (int kh = 0; kh < 5; ++kh) {
            int p = (5 * ho + kh) * 9 + w;
            unsigned both = an[p] & w4n[co * 5 + kh];
            cnt += __popc(both);
            neg += __popc((ag[p] ^ w4s[co * 5 + kh]) & both);
        }
        p2[(n * 32 + co) * 396 + rem] = (float)(cnt - 2 * neg);
    }
}

// ---------------- stage 3: bitpacked. p2 -> pack(32ch) -> conv5 -> conv6 -> p3 ----------------
// grid(512). p3: (512,64,4,9)
__global__ void stage3_kernel(const float* __restrict__ p2, const float* __restrict__ mean,
    const float* __restrict__ rstd, const float* __restrict__ g, const float* __restrict__ b,
    const float* __restrict__ ap, const unsigned* __restrict__ w5n, const unsigned* __restrict__ w5s,
    const unsigned* __restrict__ w6n, const unsigned* __restrict__ w6s, float* __restrict__ p3) {
    int n = blockIdx.x;
    float a = ap[0];
    __shared__ unsigned qn[396], qs[396];
    __shared__ unsigned an[396 * 2], ag[396 * 2];
    int t = threadIdx.x;
    for (int p = t; p < 396; p += 256) {
        unsigned nz = 0, sg = 0;
        for (int ci = 0; ci < 32; ++ci) {
            float v = p2[(n * 32 + ci) * 396 + p];
            float bnv = (v - mean[ci]) * rstd[ci] * g[ci] + b[ci];
            float pr = bnv < 0.f ? a * bnv : bnv;
            if (pr != 0.f) { nz |= 1u << ci; if (pr < 0.f) sg |= 1u << ci; }
        }
        qn[p] = nz; qs[p] = sg;
    }
    __syncthreads();
    // conv5: 32->64 ch, kh=11, pad 5 (rows 0..43); outputs packed in 2 words
    for (int u = t; u < 792; u += 256) {
        int p = u >> 1, wi = u & 1;
        int j = p / 9, w = p % 9;
        unsigned xn[11], xg[11];
#pragma unroll
        for (int kh = 0; kh < 11; ++kh) {
            int r = j - 5 + kh;
            bool v = (r >= 0 && r < 44);
            xn[kh] = v ? qn[r * 9 + w] : 0u;
            xg[kh] = v ? qs[r * 9 + w] : 0u;
        }
        unsigned onz = 0, osg = 0;
        for (int jj = 0; jj < 32; ++jj) {
            int co = wi * 32 + jj;
            int cnt = 0, neg = 0;
#pragma unroll
            for (int kh = 0; kh < 11; ++kh) {
                unsigned both = xn[kh] & w5n[co * 11 + kh];
                cnt += __popc(both);
                neg += __popc((xg[kh] ^ w5s[co * 11 + kh]) & both);
            }
            int s = cnt - 2 * neg;
            if (s != 0) { onz |= 1u << jj; if (s < 0) osg |= 1u << jj; }
        }
        an[p * 2 + wi] = onz; ag[p * 2 + wi] = osg;
    }
    __syncthreads();
    // conv6: 64->64 ch, kh=11, stride 11 -> 4 rows
    for (int o = t; o < 2304; o += 256) {
        int co = o / 36, rem = o % 36, ho = rem / 9, w = rem % 9;
        int cnt = 0, neg = 0;
        for (int kh = 0; kh < 11; ++kh) {
            int base = ((11 * ho + kh) * 9 + w) * 2;
#pragma unroll
            for (int wi = 0; wi < 2; ++wi) {
                unsigned both = an[base + wi] & w6n[(co * 11 + kh) * 2 + wi];
                cnt += __popc(both);
                neg += __popc((ag[base + wi] ^ w6s[(co * 11 + kh) * 2 + wi]) & both);
            }
        }
        p3[(n * 64 + co) * 36 + rem] = (float)(cnt - 2 * neg);
    }
}

// ---------------- stage 4: bitpacked. p3 -> pack(64ch) -> conv7 -> conv8 -> p4 ----------------
// grid(512). p4: (512,128,4,3)
__global__ void stage4_kernel(const float* __restrict__ p3, const float* __restrict__ mean,
    const float* __restrict__ rstd, const float* __restrict__ g, const float* __restrict__ b,
    const float* __restrict__ ap, const unsigned* __restrict__ w7n, const unsigned* __restrict__ w7s,
    const unsigned* __restrict__ w8n, const unsigned* __restrict__ w8s, float* __restrict__ p4) {
    int n = blockIdx.x;
    float a = ap[0];
    __shared__ unsigned q[36 * 4];                 // [p][nz0,nz1,sg0,sg1]
    __shared__ unsigned an[36 * 4], ag[36 * 4];    // a4: [p][4 words]
    int t = threadIdx.x;
    if (t < 72) {
        int p = t >> 1, half = t & 1;
        unsigned nz = 0, sg = 0;
        for (int j = 0; j < 32; ++j) {
            int ci = half * 32 + j;
            float v = p3[(n * 64 + ci) * 36 + p];
            float bnv = (v - mean[ci]) * rstd[ci] * g[ci] + b[ci];
            float pr = bnv < 0.f ? a * bnv : bnv;
            if (pr != 0.f) { nz |= 1u << j; if (pr < 0.f) sg |= 1u << j; }
        }
        q[p * 4 + half] = nz; q[p * 4 + 2 + half] = sg;
    }
    __syncthreads();
    // conv7: 64->128 ch, kw=3, pad 1 over w (0..8)
    if (t < 144) {
        int p = t >> 2, wi = t & 3;
        int h = p / 9, w = p % 9;
        unsigned onz = 0, osg = 0;
        for (int jj = 0; jj < 32; ++jj) {
            int co = wi * 32 + jj;
            int cnt = 0, neg = 0;
            for (int kw = 0; kw < 3; ++kw) {
                int wl = w + kw - 1;
                if (wl < 0 || wl >= 9) continue;
                int pi = h * 9 + wl;
#pragma unroll
                for (int iw = 0; iw < 2; ++iw) {
                    unsigned both = q[pi * 4 + iw] & w7n[(co * 3 + kw) * 2 + iw];
                    cnt += __popc(both);
                    neg += __popc((q[pi * 4 + 2 + iw] ^ w7s[(co * 3 + kw) * 2 + iw]) & both);
                }
            }
            int s = cnt - 2 * neg;
            if (s != 0) { onz |= 1u << jj; if (s < 0) osg |= 1u << jj; }
        }
        an[p * 4 + wi] = onz; ag[p * 4 + wi] = osg;
    }
    __syncthreads();
    // conv8: 128->128 ch, kw=3, stride 3 -> 3 cols
    for (int o = t; o < 1536; o += 256) {
        int co = o / 12, rem = o % 12, h = rem / 3, wo = rem % 3;
        int cnt = 0, neg = 0;
        for (int kw = 0; kw < 3; ++kw) {
            int pi = h * 9 + 3 * wo + kw;
#pragma unroll
            for (int iw = 0; iw < 4; ++iw) {
                unsigned both = an[pi * 4 + iw] & w8n[(co * 3 + kw) * 4 + iw];
                cnt += __popc(both);
                neg += __popc((ag[pi * 4 + iw] ^ w8s[(co * 3 + kw) * 4 + iw]) & both);
            }
        }
        p4[(n * 128 + co) * 12 + rem] = (float)(cnt - 2 * neg);
    }
}

// ---------------- stage 5: bitpacked. p4 -> pack(128ch) -> conv9 -> conv10 -> p5 ----------------
// grid(512). p5: (512,1024) flat, feature = co*4+h
__global__ void stage5_kernel(const float* __restrict__ p4, const float* __restrict__ mean,
    const float* __restrict__ rstd, const float* __restrict__ g, const float* __restrict__ b,
    const float* __restrict__ ap, const unsigned* __restrict__ w9n, const unsigned* __restrict__ w9s,
    const unsigned* __restrict__ w10n, const unsigned* __restrict__ w10s, float* __restrict__ p5) {
    int n = blockIdx.x;
    float a = ap[0];
    __shared__ unsigned q[12 * 8];                 // [p][nz0..3, sg0..3]
    __shared__ unsigned an[12 * 8], ag[12 * 8];
    int t = threadIdx.x;
    if (t < 48) {
        int p = t >> 2, wq = t & 3;
        unsigned nz = 0, sg = 0;
        for (int j = 0; j < 32; ++j) {
            int ci = wq * 32 + j;
            float v = p4[(n * 128 + ci) * 12 + p];
            float bnv = (v - mean[ci]) * rstd[ci] * g[ci] + b[ci];
            float pr = bnv < 0.f ? a * bnv : bnv;
            if (pr != 0.f) { nz |= 1u << j; if (pr < 0.f) sg |= 1u << j; }
        }
        q[p * 8 + wq] = nz; q[p * 8 + 4 + wq] = sg;
    }
    __syncthreads();
    // conv9: 128->256 ch, kw=3, pad 1 over w (0..2)
    if (t < 96) {
        int p = t >> 3, wi = t & 7;
        int h = p / 3, w = p % 3;
        unsigned onz = 0, osg = 0;
        for (int jj = 0; jj < 32; ++jj) {
            int co = wi * 32 + jj;
            int cnt = 0, neg = 0;
            for (int kw = 0; kw < 3; ++kw) {
                int wl = w + kw - 1;
                if (wl < 0 || wl >= 3) continue;
                int pi = h * 3 + wl;
#pragma unroll
                for (int iw = 0; iw < 4; ++iw) {
                    unsigned both = q[pi * 8 + iw] & w9n[(co * 3 + kw) * 4 + iw];
                    cnt += __popc(both);
                    neg += __popc((q[pi * 8 + 4 + iw] ^ w9s[(co * 3 + kw) * 4 + iw]) & both);
                }
            }
            int s = cnt - 2 * neg;
            if (s != 0) { onz |= 1u << jj; if (s < 0) osg |= 1u << jj; }
        }
        an[p * 8 + wi] = onz; ag[p * 8 + wi] = osg;
    }
    __syncthreads();
    // conv10: 256->256 ch, kw=3, stride 3 -> 1 col
    for (int o = t; o < 1024; o += 256) {
        int co = o >> 2, h = o & 3;
        int cnt = 0, neg = 0;
        for (int kw = 0; kw < 3; ++kw) {
            int pi = h * 3 + kw;
#pragma unroll
            for (int iw = 0; iw < 8; ++iw) {
                unsigned both = an[pi * 8 + iw] & w10n[(co * 3 + kw) * 8 + iw];
                cnt += __popc(both);
                neg += __popc((ag[pi * 8 + iw] ^ w10s[(co * 3 + kw) * 8 + iw]) & both);
            }
        }
        p5[n * 1024 + o] = (float)(cnt - 2 * neg);
    }
}

// ---------------- fc1: prelu(bn2d(p5)) @ sign(fc1).T (unchanged) ----------------
__global__ void fc1_kernel(const float* __restrict__ p5, const float* __restrict__ mean,
                           const float* __restrict__ rstd, const float* __restrict__ g,
                           const float* __restrict__ b, const float* __restrict__ ap,
                           const float* __restrict__ sfc1, float* __restrict__ h1) {
    int n = blockIdx.x;
    float a = ap[0];
    __shared__ float hv[1024];
    int t = threadIdx.x;
    for (int idx = t; idx < 1024; idx += 256) {
        int c = idx >> 2;
        float v = p5[n * 1024 + idx];
        float bnv = (v - mean[c]) * rstd[c] * g[c] + b[c];
        hv[idx] = bnv < 0.f ? a * bnv : bnv;
    }
    __syncthreads();
    int j = t;
    double s = 0.0;
    for (int k = 0; k < 1024; ++k) s += (double)(hv[k] * sfc1[j * 1024 + k]);
    h1[n * 256 + j] = (float)s;
}

// ---------------- fc2 (unchanged) ----------------
__global__ void fc2_kernel(const float* __restrict__ h1, const float* __restrict__ mean,
                           const float* __restrict__ rstd, const float* __restrict__ g,
                           const float* __restrict__ b, const float* __restrict__ ap,
                           const float* __restrict__ sfc2, float* __restrict__ h2) {
    int n = blockIdx.x;
    float a = ap[0];
    __shared__ float sv[256];
    int t = threadIdx.x;
    if (t < 256) {
        float v = h1[n * 256 + t];
        float bnv = (v - mean[t]) * rstd[t] * g[t] + b[t];
        float pr = bnv < 0.f ? a * bnv : bnv;
        sv[t] = fsign(pr);
    }
    __syncthreads();
    if (t < 64) {
        float s = 0.f;
        for (int k = 0; k < 256; ++k) s += sv[k] * sfc2[t * 256 + k];
        h2[n * 64 + t] = s;
    }
}

// ---------------- fc3 (unchanged) ----------------
__global__ void fc3_kernel(const float* __restrict__ h2, const float* __restrict__ mean,
                           const float* __restrict__ rstd, const float* __restrict__ g,
                           const float* __restrict__ b, const float* __restrict__ ap,
                           const float* __restrict__ sfc3, float* __restrict__ out) {
    int n = blockIdx.x;
    float a = ap[0];
    __shared__ float sv[64];
    int t = threadIdx.x;
    if (t < 64) {
        float v = h2[n * 64 + t];
        float bnv = (v - mean[t]) * rstd[t] * g[t] + b[t];
        float pr = bnv < 0.f ? a * bnv : bnv;
        sv[t] = fsign(pr);
    }
    __syncthreads();
    if (t < 2) {
        float s = 0.f;
        for (int k = 0; k < 64; ++k) s += sv[k] * sfc3[t * 64 + k];
        out[n * 2 + t] = s;
    }
}

extern "C" void kernel_launch(void* const* d_in, const int* in_sizes, int n_in,
                              void* d_out, int out_size, void* d_ws, size_t ws_size,
                              hipStream_t stream) {
    const float* x = (const float*)d_in[0];
    // dict order: 0:x, 1-10:w1..w10, stage i: g=11+3(i-1), b=12+3(i-1), a=13+3(i-1)
    // 26:fc1, 27:fc2, 28:fc3, 29:g6, 30:b6, 31:g7, 32:b7, 33:a6, 34:a7
    const float* G[8] = {nullptr, (const float*)d_in[11], (const float*)d_in[14],
                         (const float*)d_in[17], (const float*)d_in[20], (const float*)d_in[23],
                         (const float*)d_in[29], (const float*)d_in[31]};
    const float* B[8] = {nullptr, (const float*)d_in[12], (const float*)d_in[15],
                         (const float*)d_in[18], (const float*)d_in[21], (const float*)d_in[24],
                         (const float*)d_in[30], (const float*)d_in[32]};
    const float* A[8] = {nullptr, (const float*)d_in[13], (const float*)d_in[16],
                         (const float*)d_in[19], (const float*)d_in[22], (const float*)d_in[25],
                         (const float*)d_in[33], (const float*)d_in[34]};

    float* ws = (float*)d_ws;
    size_t off = 0;
    // float signed weights: w1, w2, fc1, fc2, fc3
    const int fsz[5] = {80, 1280, 262144, 16384, 128};
    float* fw[5];
    for (int i = 0; i < 5; ++i) { fw[i] = ws + off; off += (size_t)fsz[i]; }
    float* sw1 = fw[0]; float* sw2 = fw[1]; float* sfc1 = fw[2]; float* sfc2 = fw[3]; float* sfc3 = fw[4];

    // packed conv weights (nz, sg) for w3..w10
    const int psz[8] = {160, 160, 704, 1408, 768, 1536, 3072, 6144};
    unsigned* pn[8]; unsigned* pg[8];
    for (int i = 0; i < 8; ++i) {
        pn[i] = (unsigned*)(ws + off); off += (size_t)psz[i];
        pg[i] = (unsigned*)(ws + off); off += (size_t)psz[i];
    }

    float* p1 = ws + off; off += 16220160;   // 512*16*220*9
    float* p2 = ws + off; off += 6488064;    // 512*32*44*9
    float* p3 = ws + off; off += 1179648;    // 512*64*4*9
    float* p4 = ws + off; off += 786432;     // 512*128*4*3
    float* p5 = ws + off; off += 524288;     // 512*1024
    float* h1 = ws + off; off += 131072;     // 512*256
    float* h2 = ws + off; off += 32768;      // 512*64
    float* mean1 = ws + off; off += 16;  float* rstd1 = ws + off; off += 16;
    float* mean2 = ws + off; off += 32;  float* rstd2 = ws + off; off += 32;
    float* mean3 = ws + off; off += 64;  float* rstd3 = ws + off; off += 64;
    float* mean4 = ws + off; off += 128; float* rstd4 = ws + off; off += 128;
    float* mean5 = ws + off; off += 256; float* rstd5 = ws + off; off += 256;
    float* mean6 = ws + off; off += 256; float* rstd6 = ws + off; off += 256;
    float* mean7 = ws + off; off += 64;  float* rstd7 = ws + off; off += 64;
    if (off & 1) off += 1;  // 8B-align
    double* part = (double*)(ws + off); off += 2 * 16384;

    // 1. sign float-path weights
    WPtrs wp;
    const int fsrc_idx[5] = {1, 2, 26, 27, 28};
    for (int i = 0; i < 5; ++i) {
        wp.src[i] = (const float*)d_in[fsrc_idx[i]];
        wp.dst[i] = fw[i];
        wp.n[i] = fsz[i];
    }
    hipLaunchKernelGGL(sign_weights_kernel, dim3(32, 5), dim3(256), 0, stream, wp);

    // 2. pack conv weights w3..w10
    PWall pa;
    const int cout_[8] = {32, 32, 64, 64, 128, 128, 256, 256};
    const int cin_[8]  = {16, 32, 32, 64, 64, 128, 128, 256};
    const int kk_[8]   = {5, 5, 11, 11, 3, 3, 3, 3};
    for (int i = 0; i < 8; ++i) {
        pa.l[i].src = (const float*)d_in[3 + i];
        pa.l[i].dnz = pn[i];
        pa.l[i].dsg = pg[i];
        pa.l[i].cout = cout_[i];
        pa.l[i].cin = cin_[i];
        pa.l[i].k = kk_[i];
        pa.l[i].nw = (cin_[i] + 31) / 32;
    }
    hipLaunchKernelGGL(pack_weights_kernel, dim3(4, 8), dim3(256), 0, stream, pa);

    // 3. stage1 (float) -> p1, stats
    hipLaunchKernelGGL(stage1_kernel, dim3(22, 512), dim3(256), 0, stream, x, sw1, sw2, p1);
    hipLaunchKernelGGL(stats_partial, dim3(16, 64), dim3(256), 0, stream, p1, 16, 512, 1980, 64, part);
    hipLaunchKernelGGL(stats_final, dim3(1), dim3(256), 0, stream, part, 16, 64, (long)512 * 1980, mean1, rstd1);

    // 4. stage2 (packed)
    hipLaunchKernelGGL(stage2_kernel, dim3(512), dim3(256), 0, stream, p1, mean1, rstd1,
                       G[1], B[1], A[1], pn[0], pg[0], pn[1], pg[1], p2);
    hipLaunchKernelGGL(stats_partial, dim3(32, 64), dim3(256), 0, stream, p2, 32, 512, 396, 64, part);
    hipLaunchKernelGGL(stats_final, dim3(1), dim3(256), 0, stream, part, 32, 64, (long)512 * 396, mean2, rstd2);

    // 5. stage3 (packed)
    hipLaunchKernelGGL(stage3_kernel, dim3(512), dim3(256), 0, stream, p2, mean2, rstd2,
                       G[2], B[2], A[2], pn[2], pg[2], pn[3], pg[3], p3);
    hipLaunchKernelGGL(stats_partial, dim3(64, 16), dim3(256), 0, stream, p3, 64, 512, 36, 16, part);
    hipLaunchKernelGGL(stats_final, dim3(1), dim3(256), 0, stream, part, 64, 16, (long)512 * 36, mean3, rstd3);

    // 6. stage4 (packed)
    hipLaunchKernelGGL(stage4_kernel, dim3(512), dim3(256), 0, stream, p3, mean3, rstd3,
                       G[3], B[3], A[3], pn[4], pg[4], pn[5], pg[5], p4);
    hipLaunchKernelGGL(stats_partial, dim3(128, 16), dim3(256), 0, stream, p4, 128, 512, 12, 16, part);
    hipLaunchKernelGGL(stats_final, dim3(1), dim3(256), 0, stream, part, 128, 16, (long)512 * 12, mean4, rstd4);

    // 7. stage5 (packed)
    hipLaunchKernelGGL(stage5_kernel, dim3(512), dim3(256), 0, stream, p4, mean4, rstd4,
                       G[4], B[4], A[4], pn[6], pg[6], pn[7], pg[7], p5);
    hipLaunchKernelGGL(stats_partial, dim3(256, 8), dim3(256), 0, stream, p5, 256, 512, 4, 8, part);
    hipLaunchKernelGGL(stats_final, dim3(1), dim3(256), 0, stream, part, 256, 8, (long)512 * 4, mean5, rstd5);

    // 8. fc1
    hipLaunchKernelGGL(fc1_kernel, dim3(512), dim3(256), 0, stream, p5, mean5, rstd5,
                       G[5], B[5], A[5], sfc1, h1);
    hipLaunchKernelGGL(stats_partial, dim3(256, 1), dim3(256), 0, stream, h1, 256, 512, 1, 1, part);
    hipLaunchKernelGGL(stats_final, dim3(1), dim3(256), 0, stream, part, 256, 1, (long)512, mean6, rstd6);

    // 9. fc2
    hipLaunchKernelGGL(fc2_kernel, dim3(512), dim3(256), 0, stream, h1, mean6, rstd6,
                       G[6], B[6], A[6], sfc2, h2);
    hipLaunchKernelGGL(stats_partial, dim3(64, 1), dim3(256), 0, stream, h2, 64, 512, 1, 1, part);
    hipLaunchKernelGGL(stats_final, dim3(1), dim3(64), 0, stream, part, 64, 1, (long)512, mean7, rstd7);

    // 10. fc3 -> d_out
    hipLaunchKernelGGL(fc3_kernel, dim3(512), dim3(256), 0, stream, h2, mean7, rstd7,
                       G[7], B[7], A[7], sfc3, (float*)d_out);
}

// Round 4
// 639.671 us; speedup vs baseline: 3.6706x; 1.1960x over previous
//
#include <hip/hip_runtime.h>
#include <hip/hip_bf16.h>

#define EPSV 1e-5

__device__ __forceinline__ float fsign(float x) {
    return (float)((x > 0.f) - (x < 0.f));
}

// ---------------- sign(weights) for float-path layers (w1, w2, fc1, fc2, fc3) ----------------
struct WPtrs {
    const float* src[5];
    float* dst[5];
    int n[5];
};

__global__ void sign_weights_kernel(WPtrs wp) {
    int wi = blockIdx.y;
    int n = wp.n[wi];
    const float* s = wp.src[wi];
    float* d = wp.dst[wi];
    for (int i = blockIdx.x * blockDim.x + threadIdx.x; i < n; i += gridDim.x * blockDim.x)
        d[i] = fsign(s[i]);
}

// ---------------- pack conv weights (w3..w10) along Cin into bit words ----------------
struct PW { const float* src; unsigned* dnz; unsigned* dsg; int cout, cin, k, nw; };
struct PWall { PW l[8]; };

__global__ void pack_weights_kernel(PWall pa) {
    PW p = pa.l[blockIdx.y];
    int total = p.cout * p.k * p.nw;
    for (int u = blockIdx.x * blockDim.x + threadIdx.x; u < total; u += gridDim.x * blockDim.x) {
        int co = u / (p.k * p.nw);
        int rem = u % (p.k * p.nw);
        int kk = rem / p.nw, wi = rem % p.nw;
        unsigned nz = 0, sg = 0;
        for (int j = 0; j < 32; ++j) {
            int ci = wi * 32 + j;
            if (ci < p.cin) {
                float v = p.src[(co * p.cin + ci) * p.k + kk];
                if (v != 0.f) nz |= 1u << j;
                if (v < 0.f) sg |= 1u << j;
            }
        }
        p.dnz[u] = nz;
        p.dsg[u] = sg;
    }
}

// ---------------- stage 1: conv1(f32) + conv2(fp64-accum), all-register a1 ----------------
// x (512,1,1100,9) -> p1 (512,16,220,9). grid (8, 512): 28 output rows per block.
// Accumulation order identical to the validated round-3 version (ci asc, kh asc, (double)(f32 prod)).
__global__ void stage1_kernel(const float* __restrict__ x, const float* __restrict__ sw1,
                              const float* __restrict__ sw2, float* __restrict__ p1) {
    int n = blockIdx.y;
    int ho0 = blockIdx.x * 28;
    int nrows = min(28, 220 - ho0);
    int nrx = 5 * nrows + 4;
    __shared__ float xs[144 * 9];
    int t = threadIdx.x;
    int hbase = 5 * ho0 - 2;
    for (int i = t; i < nrx * 9; i += 256) {
        int r = i / 9, w = i - r * 9, h = hbase + r;
        xs[i] = (h >= 0 && h < 1100) ? x[(n * 1100 + h) * 9 + w] : 0.f;
    }
    __syncthreads();
    int npos = nrows * 9;
    if (t < npos) {
        int hoL = t / 9, w = t - hoL * 9;
        float xr[9];
        int base = 45 * hoL + w;
#pragma unroll
        for (int r = 0; r < 9; ++r) xr[r] = xs[base + 9 * r];
        double acc[16];
#pragma unroll
        for (int co = 0; co < 16; ++co) acc[co] = 0.0;
        for (int ci = 0; ci < 16; ++ci) {
            float a1k[5];
#pragma unroll
            for (int kh = 0; kh < 5; ++kh) {
                float s = 0.f;
#pragma unroll
                for (int k5 = 0; k5 < 5; ++k5) s += sw1[ci * 5 + k5] * xr[kh + k5];
                a1k[kh] = s;
            }
#pragma unroll
            for (int co = 0; co < 16; ++co) {
                const float* wrow = sw2 + (co * 16 + ci) * 5;
#pragma unroll
                for (int kh = 0; kh < 5; ++kh)
                    acc[co] += (double)(wrow[kh] * a1k[kh]);
            }
        }
        int ho = ho0 + hoL;
        long obase = ((long)n * 16) * 1980 + ho * 9 + w;
#pragma unroll
        for (int co = 0; co < 16; ++co)
            p1[obase + co * 1980] = (float)acc[co];
    }
}

// ---------------- BN partial stats, float4-vectorized, NCHW rows (HW % 4 == 0) ----------------
__global__ void stats_rows(const float* __restrict__ x, int C, int N, int HW, int S,
                           double* __restrict__ part) {
    int c = blockIdx.x, s = blockIdx.y;
    int nlo = (int)((long)N * s / S), nhi = (int)((long)N * (s + 1) / S);
    unsigned HW4 = (unsigned)HW >> 2;
    unsigned tot = (unsigned)(nhi - nlo) * HW4;
    double sum = 0, sq = 0;
    for (unsigned u = threadIdx.x; u < tot; u += 256) {
        unsigned nn = u / HW4, j = u - nn * HW4;
        const float4 v = ((const float4*)(x + ((long)((nlo + nn) * C + c)) * HW))[j];
        sum += v.x; sq += (double)v.x * v.x;
        sum += v.y; sq += (double)v.y * v.y;
        sum += v.z; sq += (double)v.z * v.z;
        sum += v.w; sq += (double)v.w * v.w;
    }
    __shared__ double ls[256], lq[256];
    ls[threadIdx.x] = sum;
    lq[threadIdx.x] = sq;
    __syncthreads();
    for (int off = 128; off > 0; off >>= 1) {
        if ((int)threadIdx.x < off) {
            ls[threadIdx.x] += ls[threadIdx.x + off];
            lq[threadIdx.x] += lq[threadIdx.x + off];
        }
        __syncthreads();
    }
    if (threadIdx.x == 0) {
        part[(c * S + s) * 2] = ls[0];
        part[(c * S + s) * 2 + 1] = lq[0];
    }
}

// ---------------- BN partial stats for bn1d (x[n*C + c]), one block per feature ----------------
__global__ void stats_bn1d(const float* __restrict__ x, int C, int N, double* __restrict__ part) {
    int c = blockIdx.x;
    double sum = 0, sq = 0;
    for (int n = threadIdx.x; n < N; n += 64) {
        float v = x[(long)n * C + c];
        sum += v;
        sq += (double)v * v;
    }
    for (int off = 32; off > 0; off >>= 1) {
        sum += __shfl_down(sum, off);
        sq += __shfl_down(sq, off);
    }
    if (threadIdx.x == 0) {
        part[c * 2] = sum;
        part[c * 2 + 1] = sq;
    }
}

// ---------------- derive mean/rstd from partials, per block (same math as old stats_final) ----------------
__device__ __forceinline__ void bn_from_part(const double* __restrict__ part, int C, int S,
                                             long count, float* smean, float* srstd) {
    for (int c = threadIdx.x; c < C; c += blockDim.x) {
        double s = 0, q = 0;
        for (int i = 0; i < S; ++i) {
            s += part[(c * S + i) * 2];
            q += part[(c * S + i) * 2 + 1];
        }
        double m = s / (double)count;
        double v = q / (double)count - m * m;
        smean[c] = (float)m;
        srstd[c] = (float)(1.0 / sqrt(v + EPSV));
    }
    __syncthreads();
}

// ---------------- stage 2: bitpacked. p1 -> bn-sign pack (16ch) -> conv3 -> conv4 -> p2 ----------------
__global__ void stage2_kernel(const float* __restrict__ p1, const double* __restrict__ part,
    const float* __restrict__ g, const float* __restrict__ b,
    const float* __restrict__ ap, const unsigned* __restrict__ w3n, const unsigned* __restrict__ w3s,
    const unsigned* __restrict__ w4n, const unsigned* __restrict__ w4s, float* __restrict__ p2) {
    int n = blockIdx.x;
    float a = ap[0];
    __shared__ float smean[16], srstd[16];
    bn_from_part(part, 16, 64, (long)512 * 1980, smean, srstd);
    __shared__ unsigned qn[1980], qs[1980];
    __shared__ unsigned an[1980], ag[1980];
    int t = threadIdx.x;
    for (int p = t; p < 1980; p += 256) {
        unsigned nz = 0, sg = 0;
        for (int ci = 0; ci < 16; ++ci) {
            float v = p1[(n * 16 + ci) * 1980 + p];
            float bnv = (v - smean[ci]) * srstd[ci] * g[ci] + b[ci];
            float pr = bnv < 0.f ? a * bnv : bnv;
            if (pr != 0.f) { nz |= 1u << ci; if (pr < 0.f) sg |= 1u << ci; }
        }
        qn[p] = nz; qs[p] = sg;
    }
    __syncthreads();
    // conv3: 16->32 ch, kh=5, pad 2
    for (int p = t; p < 1980; p += 256) {
        int j = p / 9, w = p % 9;
        unsigned xn[5], xg[5];
#pragma unroll
        for (int kh = 0; kh < 5; ++kh) {
            int r = j - 2 + kh;
            bool v = (r >= 0 && r < 220);
            xn[kh] = v ? qn[r * 9 + w] : 0u;
            xg[kh] = v ? qs[r * 9 + w] : 0u;
        }
        unsigned onz = 0, osg = 0;
        for (int co = 0; co < 32; ++co) {
            int cnt = 0, neg = 0;
#pragma unroll
            for (int kh = 0; kh < 5; ++kh) {
                unsigned both = xn[kh] & w3n[co * 5 + kh];
                cnt += __popc(both);
                neg += __popc((xg[kh] ^ w3s[co * 5 + kh]) & both);
            }
            int s = cnt - 2 * neg;
            if (s != 0) { onz |= 1u << co; if (s < 0) osg |= 1u << co; }
        }
        an[p] = onz; ag[p] = osg;
    }
    __syncthreads();
    // conv4: 32->32 ch, kh=5, stride 5 -> 44 rows
    for (int o = t; o < 12672; o += 256) {
        int co = o / 396, rem = o % 396, ho = rem / 9, w = rem % 9;
        int cnt = 0, neg = 0;
#pragma unroll
        for (int kh = 0; kh < 5; ++kh) {
            int p = (5 * ho + kh) * 9 + w;
            unsigned both = an[p] & w4n[co * 5 + kh];
            cnt += __popc(both);
            neg += __popc((ag[p] ^ w4s[co * 5 + kh]) & both);
        }
        p2[(n * 32 + co) * 396 + rem] = (float)(cnt - 2 * neg);
    }
}

// ---------------- stage 3: bitpacked. p2 -> pack(32ch) -> conv5 -> conv6 -> p3 ----------------
__global__ void stage3_kernel(const float* __restrict__ p2, const double* __restrict__ part,
    const float* __restrict__ g, const float* __restrict__ b,
    const float* __restrict__ ap, const unsigned* __restrict__ w5n, const unsigned* __restrict__ w5s,
    const unsigned* __restrict__ w6n, const unsigned* __restrict__ w6s, float* __restrict__ p3) {
    int n = blockIdx.x;
    float a = ap[0];
    __shared__ float smean[32], srstd[32];
    bn_from_part(part, 32, 64, (long)512 * 396, smean, srstd);
    __shared__ unsigned qn[396], qs[396];
    __shared__ unsigned an[396 * 2], ag[396 * 2];
    int t = threadIdx.x;
    for (int p = t; p < 396; p += 256) {
        unsigned nz = 0, sg = 0;
        for (int ci = 0; ci < 32; ++ci) {
            float v = p2[(n * 32 + ci) * 396 + p];
            float bnv = (v - smean[ci]) * srstd[ci] * g[ci] + b[ci];
            float pr = bnv < 0.f ? a * bnv : bnv;
            if (pr != 0.f) { nz |= 1u << ci; if (pr < 0.f) sg |= 1u << ci; }
        }
        qn[p] = nz; qs[p] = sg;
    }
    __syncthreads();
    // conv5: 32->64 ch, kh=11, pad 5
    for (int u = t; u < 792; u += 256) {
        int p = u >> 1, wi = u & 1;
        int j = p / 9, w = p % 9;
        unsigned xn[11], xg[11];
#pragma unroll
        for (int kh = 0; kh < 11; ++kh) {
            int r = j - 5 + kh;
            bool v = (r >= 0 && r < 44);
            xn[kh] = v ? qn[r * 9 + w] : 0u;
            xg[kh] = v ? qs[r * 9 + w] : 0u;
        }
        unsigned onz = 0, osg = 0;
        for (int jj = 0; jj < 32; ++jj) {
            int co = wi * 32 + jj;
            int cnt = 0, neg = 0;
#pragma unroll
            for (int kh = 0; kh < 11; ++kh) {
                unsigned both = xn[kh] & w5n[co * 11 + kh];
                cnt += __popc(both);
                neg += __popc((xg[kh] ^ w5s[co * 11 + kh]) & both);
            }
            int s = cnt - 2 * neg;
            if (s != 0) { onz |= 1u << jj; if (s < 0) osg |= 1u << jj; }
        }
        an[p * 2 + wi] = onz; ag[p * 2 + wi] = osg;
    }
    __syncthreads();
    // conv6: 64->64 ch, kh=11, stride 11 -> 4 rows
    for (int o = t; o < 2304; o += 256) {
        int co = o / 36, rem = o % 36, ho = rem / 9, w = rem % 9;
        int cnt = 0, neg = 0;
        for (int kh = 0; kh < 11; ++kh) {
            int base = ((11 * ho + kh) * 9 + w) * 2;
#pragma unroll
            for (int wi = 0; wi < 2; ++wi) {
                unsigned both = an[base + wi] & w6n[(co * 11 + kh) * 2 + wi];
                cnt += __popc(both);
                neg += __popc((ag[base + wi] ^ w6s[(co * 11 + kh) * 2 + wi]) & both);
            }
        }
        p3[(n * 64 + co) * 36 + rem] = (float)(cnt - 2 * neg);
    }
}

// ---------------- stage 4: bitpacked. p3 -> pack(64ch) -> conv7 -> conv8 -> p4 ----------------
__global__ void stage4_kernel(const float* __restrict__ p3, const double* __restrict__ part,
    const float* __restrict__ g, const float* __restrict__ b,
    const float* __restrict__ ap, const unsigned* __restrict__ w7n, const unsigned* __restrict__ w7s,
    const unsigned* __restrict__ w8n, const unsigned* __restrict__ w8s, float* __restrict__ p4) {
    int n = blockIdx.x;
    float a = ap[0];
    __shared__ float smean[64], srstd[64];
    bn_from_part(part, 64, 16, (long)512 * 36, smean, srstd);
    __shared__ unsigned q[36 * 4];
    __shared__ unsigned an[36 * 4], ag[36 * 4];
    int t = threadIdx.x;
    if (t < 72) {
        int p = t >> 1, half = t & 1;
        unsigned nz = 0, sg = 0;
        for (int j = 0; j < 32; ++j) {
            int ci = half * 32 + j;
            float v = p3[(n * 64 + ci) * 36 + p];
            float bnv = (v - smean[ci]) * srstd[ci] * g[ci] + b[ci];
            float pr = bnv < 0.f ? a * bnv : bnv;
            if (pr != 0.f) { nz |= 1u << j; if (pr < 0.f) sg |= 1u << j; }
        }
        q[p * 4 + half] = nz; q[p * 4 + 2 + half] = sg;
    }
    __syncthreads();
    // conv7: 64->128 ch, kw=3, pad 1 over w
    if (t < 144) {
        int p = t >> 2, wi = t & 3;
        int h = p / 9, w = p % 9;
        unsigned onz = 0, osg = 0;
        for (int jj = 0; jj < 32; ++jj) {
            int co = wi * 32 + jj;
            int cnt = 0, neg = 0;
            for (int kw = 0; kw < 3; ++kw) {
                int wl = w + kw - 1;
                if (wl < 0 || wl >= 9) continue;
                int pi = h * 9 + wl;
#pragma unroll
                for (int iw = 0; iw < 2; ++iw) {
                    unsigned both = q[pi * 4 + iw] & w7n[(co * 3 + kw) * 2 + iw];
                    cnt += __popc(both);
                    neg += __popc((q[pi * 4 + 2 + iw] ^ w7s[(co * 3 + kw) * 2 + iw]) & both);
                }
            }
            int s = cnt - 2 * neg;
            if (s != 0) { onz |= 1u << jj; if (s < 0) osg |= 1u << jj; }
        }
        an[p * 4 + wi] = onz; ag[p * 4 + wi] = osg;
    }
    __syncthreads();
    // conv8: 128->128 ch, kw=3, stride 3 -> 3 cols
    for (int o = t; o < 1536; o += 256) {
        int co = o / 12, rem = o % 12, h = rem / 3, wo = rem % 3;
        int cnt = 0, neg = 0;
        for (int kw = 0; kw < 3; ++kw) {
            int pi = h * 9 + 3 * wo + kw;
#pragma unroll
            for (int iw = 0; iw < 4; ++iw) {
                unsigned both = an[pi * 4 + iw] & w8n[(co * 3 + kw) * 4 + iw];
                cnt += __popc(both);
                neg += __popc((ag[pi * 4 + iw] ^ w8s[(co * 3 + kw) * 4 + iw]) & both);
            }
        }
        p4[(n * 128 + co) * 12 + rem] = (float)(cnt - 2 * neg);
    }
}

// ---------------- stage 5: bitpacked. p4 -> pack(128ch) -> conv9 -> conv10 -> p5 ----------------
__global__ void stage5_kernel(const float* __restrict__ p4, const double* __restrict__ part,
    const float* __restrict__ g, const float* __restrict__ b,
    const float* __restrict__ ap, const unsigned* __restrict__ w9n, const unsigned* __restrict__ w9s,
    const unsigned* __restrict__ w10n, const unsigned* __restrict__ w10s, float* __restrict__ p5) {
    int n = blockIdx.x;
    float a = ap[0];
    __shared__ float smean[128], srstd[128];
    bn_from_part(part, 128, 16, (long)512 * 12, smean, srstd);
    __shared__ unsigned q[12 * 8];
    __shared__ unsigned an[12 * 8], ag[12 * 8];
    int t = threadIdx.x;
    if (t < 48) {
        int p = t >> 2, wq = t & 3;
        unsigned nz = 0, sg = 0;
        for (int j = 0; j < 32; ++j) {
            int ci = wq * 32 + j;
            float v = p4[(n * 128 + ci) * 12 + p];
            float bnv = (v - smean[ci]) * srstd[ci] * g[ci] + b[ci];
            float pr = bnv < 0.f ? a * bnv : bnv;
            if (pr != 0.f) { nz |= 1u << j; if (pr < 0.f) sg |= 1u << j; }
        }
        q[p * 8 + wq] = nz; q[p * 8 + 4 + wq] = sg;
    }
    __syncthreads();
    // conv9: 128->256 ch, kw=3, pad 1 over w
    if (t < 96) {
        int p = t >> 3, wi = t & 7;
        int h = p / 3, w = p % 3;
        unsigned onz = 0, osg = 0;
        for (int jj = 0; jj < 32; ++jj) {
            int co = wi * 32 + jj;
            int cnt = 0, neg = 0;
            for (int kw = 0; kw < 3; ++kw) {
                int wl = w + kw - 1;
                if (wl < 0 || wl >= 3) continue;
                int pi = h * 3 + wl;
#pragma unroll
                for (int iw = 0; iw < 4; ++iw) {
                    unsigned both = q[pi * 8 + iw] & w9n[(co * 3 + kw) * 4 + iw];
                    cnt += __popc(both);
                    neg += __popc((q[pi * 8 + 4 + iw] ^ w9s[(co * 3 + kw) * 4 + iw]) & both);
                }
            }
            int s = cnt - 2 * neg;
            if (s != 0) { onz |= 1u << jj; if (s < 0) osg |= 1u << jj; }
        }
        an[p * 8 + wi] = onz; ag[p * 8 + wi] = osg;
    }
    __syncthreads();
    // conv10: 256->256 ch, kw=3, stride 3 -> 1 col
    for (int o = t; o < 1024; o += 256) {
        int co = o >> 2, h = o & 3;
        int cnt = 0, neg = 0;
        for (int kw = 0; kw < 3; ++kw) {
            int pi = h * 3 + kw;
#pragma unroll
            for (int iw = 0; iw < 8; ++iw) {
                unsigned both = an[pi * 8 + iw] & w10n[(co * 3 + kw) * 8 + iw];
                cnt += __popc(both);
                neg += __popc((ag[pi * 8 + iw] ^ w10s[(co * 3 + kw) * 8 + iw]) & both);
            }
        }
        p5[n * 1024 + o] = (float)(cnt - 2 * neg);
    }
}

// ---------------- fc1: prelu(bn2d(p5)) @ sign(fc1).T ----------------
__global__ void fc1_kernel(const float* __restrict__ p5, const double* __restrict__ part,
                           const float* __restrict__ g, const float* __restrict__ b,
                           const float* __restrict__ ap,
                           const float* __restrict__ sfc1, float* __restrict__ h1) {
    int n = blockIdx.x;
    float a = ap[0];
    __shared__ float smean[256], srstd[256];
    bn_from_part(part, 256, 8, (long)512 * 4, smean, srstd);
    __shared__ float hv[1024];
    int t = threadIdx.x;
    for (int idx = t; idx < 1024; idx += 256) {
        int c = idx >> 2;
        float v = p5[n * 1024 + idx];
        float bnv = (v - smean[c]) * srstd[c] * g[c] + b[c];
        hv[idx] = bnv < 0.f ? a * bnv : bnv;
    }
    __syncthreads();
    int j = t;
    double s = 0.0;
    for (int k = 0; k < 1024; ++k) s += (double)(hv[k] * sfc1[j * 1024 + k]);
    h1[n * 256 + j] = (float)s;
}

// ---------------- fc2 ----------------
__global__ void fc2_kernel(const float* __restrict__ h1, const double* __restrict__ part,
                           const float* __restrict__ g, const float* __restrict__ b,
                           const float* __restrict__ ap,
                           const float* __restrict__ sfc2, float* __restrict__ h2) {
    int n = blockIdx.x;
    float a = ap[0];
    __shared__ float smean[256], srstd[256];
    bn_from_part(part, 256, 1, (long)512, smean, srstd);
    __shared__ float sv[256];
    int t = threadIdx.x;
    if (t < 256) {
        float v = h1[n * 256 + t];
        float bnv = (v - smean[t]) * srstd[t] * g[t] + b[t];
        float pr = bnv < 0.f ? a * bnv : bnv;
        sv[t] = fsign(pr);
    }
    __syncthreads();
    if (t < 64) {
        float s = 0.f;
        for (int k = 0; k < 256; ++k) s += sv[k] * sfc2[t * 256 + k];
        h2[n * 64 + t] = s;
    }
}

// ---------------- fc3 ----------------
__global__ void fc3_kernel(const float* __restrict__ h2, const double* __restrict__ part,
                           const float* __restrict__ g, const float* __restrict__ b,
                           const float* __restrict__ ap,
                           const float* __restrict__ sfc3, float* __restrict__ out) {
    int n = blockIdx.x;
    float a = ap[0];
    __shared__ float smean[64], srstd[64];
    bn_from_part(part, 64, 1, (long)512, smean, srstd);
    __shared__ float sv[64];
    int t = threadIdx.x;
    if (t < 64) {
        float v = h2[n * 64 + t];
        float bnv = (v - smean[t]) * srstd[t] * g[t] + b[t];
        float pr = bnv < 0.f ? a * bnv : bnv;
        sv[t] = fsign(pr);
    }
    __syncthreads();
    if (t < 2) {
        float s = 0.f;
        for (int k = 0; k < 64; ++k) s += sv[k] * sfc3[t * 64 + k];
        out[n * 2 + t] = s;
    }
}

extern "C" void kernel_launch(void* const* d_in, const int* in_sizes, int n_in,
                              void* d_out, int out_size, void* d_ws, size_t ws_size,
                              hipStream_t stream) {
    const float* x = (const float*)d_in[0];
    // dict order: 0:x, 1-10:w1..w10, stage i: g=11+3(i-1), b=12+3(i-1), a=13+3(i-1)
    // 26:fc1, 27:fc2, 28:fc3, 29:g6, 30:b6, 31:g7, 32:b7, 33:a6, 34:a7
    const float* G[8] = {nullptr, (const float*)d_in[11], (const float*)d_in[14],
                         (const float*)d_in[17], (const float*)d_in[20], (const float*)d_in[23],
                         (const float*)d_in[29], (const float*)d_in[31]};
    const float* B[8] = {nullptr, (const float*)d_in[12], (const float*)d_in[15],
                         (const float*)d_in[18], (const float*)d_in[21], (const float*)d_in[24],
                         (const float*)d_in[30], (const float*)d_in[32]};
    const float* A[8] = {nullptr, (const float*)d_in[13], (const float*)d_in[16],
                         (const float*)d_in[19], (const float*)d_in[22], (const float*)d_in[25],
                         (const float*)d_in[33], (const float*)d_in[34]};

    float* ws = (float*)d_ws;
    size_t off = 0;
    const int fsz[5] = {80, 1280, 262144, 16384, 128};
    float* fw[5];
    for (int i = 0; i < 5; ++i) { fw[i] = ws + off; off += (size_t)fsz[i]; }
    float* sw1 = fw[0]; float* sw2 = fw[1]; float* sfc1 = fw[2]; float* sfc2 = fw[3]; float* sfc3 = fw[4];

    const int psz[8] = {160, 160, 704, 1408, 768, 1536, 3072, 6144};
    unsigned* pn[8]; unsigned* pg[8];
    for (int i = 0; i < 8; ++i) {
        pn[i] = (unsigned*)(ws + off); off += (size_t)psz[i];
        pg[i] = (unsigned*)(ws + off); off += (size_t)psz[i];
    }

    float* p1 = ws + off; off += 16220160;   // 512*16*220*9
    float* p2 = ws + off; off += 6488064;    // 512*32*44*9
    float* p3 = ws + off; off += 1179648;    // 512*64*4*9
    float* p4 = ws + off; off += 786432;     // 512*128*4*3
    float* p5 = ws + off; off += 524288;     // 512*1024
    float* h1 = ws + off; off += 131072;     // 512*256
    float* h2 = ws + off; off += 32768;      // 512*64
    if (off & 1) off += 1;  // 8B-align
    double* part = (double*)(ws + off); off += 2 * 16384;

    // 1. sign float-path weights
    WPtrs wp;
    const int fsrc_idx[5] = {1, 2, 26, 27, 28};
    for (int i = 0; i < 5; ++i) {
        wp.src[i] = (const float*)d_in[fsrc_idx[i]];
        wp.dst[i] = fw[i];
        wp.n[i] = fsz[i];
    }
    hipLaunchKernelGGL(sign_weights_kernel, dim3(32, 5), dim3(256), 0, stream, wp);

    // 2. pack conv weights w3..w10
    PWall pa;
    const int cout_[8] = {32, 32, 64, 64, 128, 128, 256, 256};
    const int cin_[8]  = {16, 32, 32, 64, 64, 128, 128, 256};
    const int kk_[8]   = {5, 5, 11, 11, 3, 3, 3, 3};
    for (int i = 0; i < 8; ++i) {
        pa.l[i].src = (const float*)d_in[3 + i];
        pa.l[i].dnz = pn[i];
        pa.l[i].dsg = pg[i];
        pa.l[i].cout = cout_[i];
        pa.l[i].cin = cin_[i];
        pa.l[i].k = kk_[i];
        pa.l[i].nw = (cin_[i] + 31) / 32;
    }
    hipLaunchKernelGGL(pack_weights_kernel, dim3(4, 8), dim3(256), 0, stream, pa);

    // 3. stage1 -> p1, stats
    hipLaunchKernelGGL(stage1_kernel, dim3(8, 512), dim3(256), 0, stream, x, sw1, sw2, p1);
    hipLaunchKernelGGL(stats_rows, dim3(16, 64), dim3(256), 0, stream, p1, 16, 512, 1980, 64, part);

    // 4. stage2 -> p2, stats
    hipLaunchKernelGGL(stage2_kernel, dim3(512), dim3(256), 0, stream, p1, part,
                       G[1], B[1], A[1], pn[0], pg[0], pn[1], pg[1], p2);
    hipLaunchKernelGGL(stats_rows, dim3(32, 64), dim3(256), 0, stream, p2, 32, 512, 396, 64, part);

    // 5. stage3 -> p3, stats
    hipLaunchKernelGGL(stage3_kernel, dim3(512), dim3(256), 0, stream, p2, part,
                       G[2], B[2], A[2], pn[2], pg[2], pn[3], pg[3], p3);
    hipLaunchKernelGGL(stats_rows, dim3(64, 16), dim3(256), 0, stream, p3, 64, 512, 36, 16, part);

    // 6. stage4 -> p4, stats
    hipLaunchKernelGGL(stage4_kernel, dim3(512), dim3(256), 0, stream, p3, part,
                       G[3], B[3], A[3], pn[4], pg[4], pn[5], pg[5], p4);
    hipLaunchKernelGGL(stats_rows, dim3(128, 16), dim3(256), 0, stream, p4, 128, 512, 12, 16, part);

    // 7. stage5 -> p5, stats
    hipLaunchKernelGGL(stage5_kernel, dim3(512), dim3(256), 0, stream, p4, part,
                       G[4], B[4], A[4], pn[6], pg[6], pn[7], pg[7], p5);
    hipLaunchKernelGGL(stats_rows, dim3(256, 8), dim3(256), 0, stream, p5, 256, 512, 4, 8, part);

    // 8. fc1 -> h1, stats
    hipLaunchKernelGGL(fc1_kernel, dim3(512), dim3(256), 0, stream, p5, part,
                       G[5], B[5], A[5], sfc1, h1);
    hipLaunchKernelGGL(stats_bn1d, dim3(256), dim3(64), 0, stream, h1, 256, 512, part);

    // 9. fc2 -> h2, stats
    hipLaunchKernelGGL(fc2_kernel, dim3(512), dim3(256), 0, stream, h1, part,
                       G[6], B[6], A[6], sfc2, h2);
    hipLaunchKernelGGL(stats_bn1d, dim3(64), dim3(64), 0, stream, h2, 64, 512, part);

    // 10. fc3 -> d_out
    hipLaunchKernelGGL(fc3_kernel, dim3(512), dim3(256), 0, stream, h2, part,
                       G[7], B[7], A[7], sfc3, (float*)d_out);
}

// Round 5
// 542.666 us; speedup vs baseline: 4.3268x; 1.1788x over previous
//
#include <hip/hip_runtime.h>
#include <hip/hip_bf16.h>

#define EPSV 1e-5

__device__ __forceinline__ float fsign(float x) {
    return (float)((x > 0.f) - (x < 0.f));
}

// ---------------- sign(weights) for float-path layers (w1, w2, fc1, fc2, fc3) ----------------
struct WPtrs {
    const float* src[5];
    float* dst[5];
    int n[5];
};

__global__ void sign_weights_kernel(WPtrs wp) {
    int wi = blockIdx.y;
    int n = wp.n[wi];
    const float* s = wp.src[wi];
    float* d = wp.dst[wi];
    for (int i = blockIdx.x * blockDim.x + threadIdx.x; i < n; i += gridDim.x * blockDim.x)
        d[i] = fsign(s[i]);
}

// ---------------- pack conv weights (w3..w10) along Cin into bit words ----------------
struct PW { const float* src; unsigned* dnz; unsigned* dsg; int cout, cin, k, nw; };
struct PWall { PW l[8]; };

__global__ void pack_weights_kernel(PWall pa) {
    PW p = pa.l[blockIdx.y];
    int total = p.cout * p.k * p.nw;
    for (int u = blockIdx.x * blockDim.x + threadIdx.x; u < total; u += gridDim.x * blockDim.x) {
        int co = u / (p.k * p.nw);
        int rem = u % (p.k * p.nw);
        int kk = rem / p.nw, wi = rem % p.nw;
        unsigned nz = 0, sg = 0;
        for (int j = 0; j < 32; ++j) {
            int ci = wi * 32 + j;
            if (ci < p.cin) {
                float v = p.src[(co * p.cin + ci) * p.k + kk];
                if (v != 0.f) nz |= 1u << j;
                if (v < 0.f) sg |= 1u << j;
            }
        }
        p.dnz[u] = nz;
        p.dsg[u] = sg;
    }
}

// ---------------- stage 1: conv1(f32) + conv2(fp64-accum), all-register a1 ----------------
__global__ void stage1_kernel(const float* __restrict__ x, const float* __restrict__ sw1,
                              const float* __restrict__ sw2, float* __restrict__ p1) {
    int n = blockIdx.y;
    int ho0 = blockIdx.x * 28;
    int nrows = min(28, 220 - ho0);
    int nrx = 5 * nrows + 4;
    __shared__ float xs[144 * 9];
    int t = threadIdx.x;
    int hbase = 5 * ho0 - 2;
    for (int i = t; i < nrx * 9; i += 256) {
        int r = i / 9, w = i - r * 9, h = hbase + r;
        xs[i] = (h >= 0 && h < 1100) ? x[(n * 1100 + h) * 9 + w] : 0.f;
    }
    __syncthreads();
    int npos = nrows * 9;
    if (t < npos) {
        int hoL = t / 9, w = t - hoL * 9;
        float xr[9];
        int base = 45 * hoL + w;
#pragma unroll
        for (int r = 0; r < 9; ++r) xr[r] = xs[base + 9 * r];
        double acc[16];
#pragma unroll
        for (int co = 0; co < 16; ++co) acc[co] = 0.0;
        for (int ci = 0; ci < 16; ++ci) {
            float a1k[5];
#pragma unroll
            for (int kh = 0; kh < 5; ++kh) {
                float s = 0.f;
#pragma unroll
                for (int k5 = 0; k5 < 5; ++k5) s += sw1[ci * 5 + k5] * xr[kh + k5];
                a1k[kh] = s;
            }
#pragma unroll
            for (int co = 0; co < 16; ++co) {
                const float* wrow = sw2 + (co * 16 + ci) * 5;
#pragma unroll
                for (int kh = 0; kh < 5; ++kh)
                    acc[co] += (double)(wrow[kh] * a1k[kh]);
            }
        }
        int ho = ho0 + hoL;
        long obase = ((long)n * 16) * 1980 + ho * 9 + w;
#pragma unroll
        for (int co = 0; co < 16; ++co)
            p1[obase + co * 1980] = (float)acc[co];
    }
}

// ---------------- BN partial stats, float4-vectorized, NCHW rows ----------------
__global__ void stats_rows(const float* __restrict__ x, int C, int N, int HW, int S,
                           double* __restrict__ part) {
    int c = blockIdx.x, s = blockIdx.y;
    int nlo = (int)((long)N * s / S), nhi = (int)((long)N * (s + 1) / S);
    unsigned HW4 = (unsigned)HW >> 2;
    unsigned tot = (unsigned)(nhi - nlo) * HW4;
    double sum = 0, sq = 0;
    for (unsigned u = threadIdx.x; u < tot; u += 256) {
        unsigned nn = u / HW4, j = u - nn * HW4;
        const float4 v = ((const float4*)(x + ((long)((nlo + nn) * C + c)) * HW))[j];
        sum += v.x; sq += (double)v.x * v.x;
        sum += v.y; sq += (double)v.y * v.y;
        sum += v.z; sq += (double)v.z * v.z;
        sum += v.w; sq += (double)v.w * v.w;
    }
    __shared__ double ls[256], lq[256];
    ls[threadIdx.x] = sum;
    lq[threadIdx.x] = sq;
    __syncthreads();
    for (int off = 128; off > 0; off >>= 1) {
        if ((int)threadIdx.x < off) {
            ls[threadIdx.x] += ls[threadIdx.x + off];
            lq[threadIdx.x] += lq[threadIdx.x + off];
        }
        __syncthreads();
    }
    if (threadIdx.x == 0) {
        part[(c * S + s) * 2] = ls[0];
        part[(c * S + s) * 2 + 1] = lq[0];
    }
}

__global__ void stats_final(const double* __restrict__ part, int C, int S, long count,
                            float* __restrict__ mean, float* __restrict__ rstd) {
    int c = blockIdx.x * blockDim.x + threadIdx.x;
    if (c >= C) return;
    double s = 0, q = 0;
    for (int i = 0; i < S; ++i) {
        s += part[(c * S + i) * 2];
        q += part[(c * S + i) * 2 + 1];
    }
    double m = s / (double)count;
    double v = q / (double)count - m * m;
    mean[c] = (float)m;
    rstd[c] = (float)(1.0 / sqrt(v + EPSV));
}

// ---------------- BN stats for bn1d (x[n*C + c]), one block per feature; writes mean/rstd ----------------
__global__ void stats_bn1d(const float* __restrict__ x, int C, int N,
                           float* __restrict__ mean, float* __restrict__ rstd) {
    int c = blockIdx.x;
    double sum = 0, sq = 0;
    for (int n = threadIdx.x; n < N; n += 64) {
        float v = x[(long)n * C + c];
        sum += v;
        sq += (double)v * v;
    }
    for (int off = 32; off > 0; off >>= 1) {
        sum += __shfl_down(sum, off);
        sq += __shfl_down(sq, off);
    }
    if (threadIdx.x == 0) {
        double m = sum / (double)N;
        double v = sq / (double)N - m * m;
        mean[c] = (float)m;
        rstd[c] = (float)(1.0 / sqrt(v + EPSV));
    }
}

// ---------------- stage 2: grid(11,512): 4 conv4-output rows per block ----------------
__global__ void stage2_kernel(const float* __restrict__ p1, const float* __restrict__ mean,
    const float* __restrict__ rstd, const float* __restrict__ g, const float* __restrict__ b,
    const float* __restrict__ ap, const unsigned* __restrict__ w3n, const unsigned* __restrict__ w3s,
    const unsigned* __restrict__ w4n, const unsigned* __restrict__ w4s, float* __restrict__ p2) {
    int hb = blockIdx.x;   // 0..10
    int n = blockIdx.y;
    float a = ap[0];
    __shared__ unsigned qn[216], qs[216];   // p1 rows 20hb-2 .. 20hb+21
    __shared__ unsigned an[180], ag[180];   // conv3 rows 20hb .. 20hb+19
    int t = threadIdx.x;
    if (t < 216) {
        int rl = t / 9, w = t % 9;
        int r = 20 * hb - 2 + rl;
        unsigned nz = 0, sg = 0;
        if (r >= 0 && r < 220) {
            for (int ci = 0; ci < 16; ++ci) {
                float v = p1[(n * 16 + ci) * 1980 + r * 9 + w];
                float bnv = (v - mean[ci]) * rstd[ci] * g[ci] + b[ci];
                float pr = bnv < 0.f ? a * bnv : bnv;
                if (pr != 0.f) { nz |= 1u << ci; if (pr < 0.f) sg |= 1u << ci; }
            }
        }
        qn[t] = nz; qs[t] = sg;
    }
    __syncthreads();
    // conv3: local rows jl 0..19 (global 20hb+jl), inputs local rows jl..jl+4
    if (t < 180) {
        int jl = t / 9, w = t % 9;
        unsigned onz = 0, osg = 0;
        for (int co = 0; co < 32; ++co) {
            int cnt = 0, neg = 0;
#pragma unroll
            for (int kh = 0; kh < 5; ++kh) {
                int p = (jl + kh) * 9 + w;
                unsigned both = qn[p] & w3n[co * 5 + kh];
                cnt += __popc(both);
                neg += __popc((qs[p] ^ w3s[co * 5 + kh]) & both);
            }
            int s = cnt - 2 * neg;
            if (s != 0) { onz |= 1u << co; if (s < 0) osg |= 1u << co; }
        }
        an[t] = onz; ag[t] = osg;
    }
    __syncthreads();
    // conv4: rows 4hb..4hb+3, co 0..31, w 0..8 -> 1152 items; conv3 local row = 5*hol + kh
    for (int o = t; o < 1152; o += 256) {
        int co = o / 36, rem = o % 36, hol = rem / 9, w = rem % 9;
        int cnt = 0, neg = 0;
#pragma unroll
        for (int kh = 0; kh < 5; ++kh) {
            int p = (5 * hol + kh) * 9 + w;
            unsigned both = an[p] & w4n[co * 5 + kh];
            cnt += __popc(both);
            neg += __popc((ag[p] ^ w4s[co * 5 + kh]) & both);
        }
        p2[(n * 32 + co) * 396 + (4 * hb + hol) * 9 + w] = (float)(cnt - 2 * neg);
    }
}

// ---------------- stage 3: grid(4,512): 1 conv6-output row per block ----------------
__global__ void stage3_kernel(const float* __restrict__ p2, const float* __restrict__ mean,
    const float* __restrict__ rstd, const float* __restrict__ g, const float* __restrict__ b,
    const float* __restrict__ ap, const unsigned* __restrict__ w5n, const unsigned* __restrict__ w5s,
    const unsigned* __restrict__ w6n, const unsigned* __restrict__ w6s, float* __restrict__ p3) {
    int ho = blockIdx.x;   // 0..3
    int n = blockIdx.y;
    float a = ap[0];
    __shared__ unsigned qn[189], qs[189];       // p2 rows 11ho-5 .. 11ho+15
    __shared__ unsigned an[99 * 2], ag[99 * 2]; // conv5 rows 11ho .. 11ho+10
    int t = threadIdx.x;
    if (t < 189) {
        int rl = t / 9, w = t % 9;
        int r = 11 * ho - 5 + rl;
        unsigned nz = 0, sg = 0;
        if (r >= 0 && r < 44) {
            for (int ci = 0; ci < 32; ++ci) {
                float v = p2[(n * 32 + ci) * 396 + r * 9 + w];
                float bnv = (v - mean[ci]) * rstd[ci] * g[ci] + b[ci];
                float pr = bnv < 0.f ? a * bnv : bnv;
                if (pr != 0.f) { nz |= 1u << ci; if (pr < 0.f) sg |= 1u << ci; }
            }
        }
        qn[t] = nz; qs[t] = sg;
    }
    __syncthreads();
    // conv5: local rows jl 0..10 (global 11ho+jl), inputs local rows jl..jl+10
    if (t < 198) {
        int p = t >> 1, wi = t & 1;
        int jl = p / 9, w = p % 9;
        unsigned onz = 0, osg = 0;
        for (int jj = 0; jj < 32; ++jj) {
            int co = wi * 32 + jj;
            int cnt = 0, neg = 0;
#pragma unroll
            for (int kh = 0; kh < 11; ++kh) {
                int q = (jl + kh) * 9 + w;
                unsigned both = qn[q] & w5n[co * 11 + kh];
                cnt += __popc(both);
                neg += __popc((qs[q] ^ w5s[co * 11 + kh]) & both);
            }
            int s = cnt - 2 * neg;
            if (s != 0) { onz |= 1u << jj; if (s < 0) osg |= 1u << jj; }
        }
        an[p * 2 + wi] = onz; ag[p * 2 + wi] = osg;
    }
    __syncthreads();
    // conv6: co 0..63, w 0..8 -> 576 items; conv5 local row = kh
    for (int o = t; o < 576; o += 256) {
        int co = o / 9, w = o % 9;
        int cnt = 0, neg = 0;
        for (int kh = 0; kh < 11; ++kh) {
            int base = (kh * 9 + w) * 2;
#pragma unroll
            for (int wi = 0; wi < 2; ++wi) {
                unsigned both = an[base + wi] & w6n[(co * 11 + kh) * 2 + wi];
                cnt += __popc(both);
                neg += __popc((ag[base + wi] ^ w6s[(co * 11 + kh) * 2 + wi]) & both);
            }
        }
        p3[(n * 64 + co) * 36 + ho * 9 + w] = (float)(cnt - 2 * neg);
    }
}

// ---------------- stage 4: grid(4,512): one h-row per block (1x3 convs: rows independent) ----------------
__global__ void stage4_kernel(const float* __restrict__ p3, const float* __restrict__ mean,
    const float* __restrict__ rstd, const float* __restrict__ g, const float* __restrict__ b,
    const float* __restrict__ ap, const unsigned* __restrict__ w7n, const unsigned* __restrict__ w7s,
    const unsigned* __restrict__ w8n, const unsigned* __restrict__ w8s, float* __restrict__ p4) {
    int h = blockIdx.x;   // 0..3
    int n = blockIdx.y;
    float a = ap[0];
    __shared__ unsigned q[9 * 4];      // [w][nz0,nz1,sg0,sg1]
    __shared__ signed char strit[9 * 128];
    __shared__ unsigned an[9 * 4], ag[9 * 4];
    int t = threadIdx.x;
    if (t < 18) {
        int w = t >> 1, half = t & 1;
        unsigned nz = 0, sg = 0;
        for (int j = 0; j < 32; ++j) {
            int ci = half * 32 + j;
            float v = p3[(n * 64 + ci) * 36 + h * 9 + w];
            float bnv = (v - mean[ci]) * rstd[ci] * g[ci] + b[ci];
            float pr = bnv < 0.f ? a * bnv : bnv;
            if (pr != 0.f) { nz |= 1u << j; if (pr < 0.f) sg |= 1u << j; }
        }
        q[w * 4 + half] = nz; q[w * 4 + 2 + half] = sg;
    }
    __syncthreads();
    // conv7 per (w, co): 9*128 = 1152 items
    for (int o = t; o < 1152; o += 256) {
        int w = o / 128, co = o % 128;
        int cnt = 0, neg = 0;
        for (int kw = 0; kw < 3; ++kw) {
            int wl = w + kw - 1;
            if (wl < 0 || wl >= 9) continue;
#pragma unroll
            for (int iw = 0; iw < 2; ++iw) {
                unsigned both = q[wl * 4 + iw] & w7n[(co * 3 + kw) * 2 + iw];
                cnt += __popc(both);
                neg += __popc((q[wl * 4 + 2 + iw] ^ w7s[(co * 3 + kw) * 2 + iw]) & both);
            }
        }
        int s = cnt - 2 * neg;
        strit[o] = (signed char)((s > 0) - (s < 0));
    }
    __syncthreads();
    if (t < 36) {
        int w = t >> 2, wi = t & 3;
        unsigned nz = 0, sg = 0;
        for (int j = 0; j < 32; ++j) {
            int tr = strit[w * 128 + wi * 32 + j];
            if (tr) { nz |= 1u << j; if (tr < 0) sg |= 1u << j; }
        }
        an[w * 4 + wi] = nz; ag[w * 4 + wi] = sg;
    }
    __syncthreads();
    // conv8 per (co, wo): 128*3 = 384 items
    for (int o = t; o < 384; o += 256) {
        int co = o / 3, wo = o % 3;
        int cnt = 0, neg = 0;
        for (int kw = 0; kw < 3; ++kw) {
            int wl = 3 * wo + kw;
#pragma unroll
            for (int iw = 0; iw < 4; ++iw) {
                unsigned both = an[wl * 4 + iw] & w8n[(co * 3 + kw) * 4 + iw];
                cnt += __popc(both);
                neg += __popc((ag[wl * 4 + iw] ^ w8s[(co * 3 + kw) * 4 + iw]) & both);
            }
        }
        p4[(n * 128 + co) * 12 + h * 3 + wo] = (float)(cnt - 2 * neg);
    }
}

// ---------------- stage 5: grid(4,512): one h-row per block ----------------
__global__ void stage5_kernel(const float* __restrict__ p4, const float* __restrict__ mean,
    const float* __restrict__ rstd, const float* __restrict__ g, const float* __restrict__ b,
    const float* __restrict__ ap, const unsigned* __restrict__ w9n, const unsigned* __restrict__ w9s,
    const unsigned* __restrict__ w10n, const unsigned* __restrict__ w10s, float* __restrict__ p5) {
    int h = blockIdx.x;   // 0..3
    int n = blockIdx.y;
    float a = ap[0];
    __shared__ unsigned q[3 * 8];      // [w][nz0..3, sg0..3]
    __shared__ signed char strit[3 * 256];
    __shared__ unsigned an[3 * 8], ag[3 * 8];
    int t = threadIdx.x;
    if (t < 12) {
        int w = t >> 2, wq = t & 3;
        unsigned nz = 0, sg = 0;
        for (int j = 0; j < 32; ++j) {
            int ci = wq * 32 + j;
            float v = p4[(n * 128 + ci) * 12 + h * 3 + w];
            float bnv = (v - mean[ci]) * rstd[ci] * g[ci] + b[ci];
            float pr = bnv < 0.f ? a * bnv : bnv;
            if (pr != 0.f) { nz |= 1u << j; if (pr < 0.f) sg |= 1u << j; }
        }
        q[w * 8 + wq] = nz; q[w * 8 + 4 + wq] = sg;
    }
    __syncthreads();
    // conv9 per (w, co): 3*256 = 768 items
    for (int o = t; o < 768; o += 256) {
        int w = o / 256, co = o % 256;
        int cnt = 0, neg = 0;
        for (int kw = 0; kw < 3; ++kw) {
            int wl = w + kw - 1;
            if (wl < 0 || wl >= 3) continue;
#pragma unroll
            for (int iw = 0; iw < 4; ++iw) {
                unsigned both = q[wl * 8 + iw] & w9n[(co * 3 + kw) * 4 + iw];
                cnt += __popc(both);
                neg += __popc((q[wl * 8 + 4 + iw] ^ w9s[(co * 3 + kw) * 4 + iw]) & both);
            }
        }
        int s = cnt - 2 * neg;
        strit[o] = (signed char)((s > 0) - (s < 0));
    }
    __syncthreads();
    if (t < 24) {
        int w = t >> 3, wi = t & 7;
        unsigned nz = 0, sg = 0;
        for (int j = 0; j < 32; ++j) {
            int tr = strit[w * 256 + wi * 32 + j];
            if (tr) { nz |= 1u << j; if (tr < 0) sg |= 1u << j; }
        }
        an[w * 8 + wi] = nz; ag[w * 8 + wi] = sg;
    }
    __syncthreads();
    // conv10 per co: 256 items (output col 0 only: inputs w = kw)
    if (t < 256) {
        int co = t;
        int cnt = 0, neg = 0;
        for (int kw = 0; kw < 3; ++kw) {
#pragma unroll
            for (int iw = 0; iw < 8; ++iw) {
                unsigned both = an[kw * 8 + iw] & w10n[(co * 3 + kw) * 8 + iw];
                cnt += __popc(both);
                neg += __popc((ag[kw * 8 + iw] ^ w10s[(co * 3 + kw) * 8 + iw]) & both);
            }
        }
        p5[n * 1024 + co * 4 + h] = (float)(cnt - 2 * neg);
    }
}

// ---------------- fc1: prelu(bn2d(p5)) @ sign(fc1).T, wave-per-output ----------------
__global__ void fc1_kernel(const float* __restrict__ p5, const float* __restrict__ mean,
                           const float* __restrict__ rstd, const float* __restrict__ g,
                           const float* __restrict__ b, const float* __restrict__ ap,
                           const float* __restrict__ sfc1, float* __restrict__ h1) {
    int n = blockIdx.x;
    float a = ap[0];
    __shared__ float hv[1024];
    int t = threadIdx.x;
    for (int idx = t; idx < 1024; idx += 256) {
        int c = idx >> 2;
        float v = p5[n * 1024 + idx];
        float bnv = (v - mean[c]) * rstd[c] * g[c] + b[c];
        hv[idx] = bnv < 0.f ? a * bnv : bnv;
    }
    __syncthreads();
    int wave = t >> 6, lane = t & 63;
    float hr[16];
#pragma unroll
    for (int m = 0; m < 16; ++m) hr[m] = hv[lane * 16 + m];
    for (int jj = 0; jj < 64; ++jj) {
        int j = wave * 64 + jj;
        const float4* wr = (const float4*)(sfc1 + (j << 10) + (lane << 4));
        double s = 0.0;
#pragma unroll
        for (int q4 = 0; q4 < 4; ++q4) {
            float4 wv = wr[q4];
            s += (double)(hr[q4 * 4 + 0] * wv.x);
            s += (double)(hr[q4 * 4 + 1] * wv.y);
            s += (double)(hr[q4 * 4 + 2] * wv.z);
            s += (double)(hr[q4 * 4 + 3] * wv.w);
        }
#pragma unroll
        for (int off = 32; off > 0; off >>= 1) s += __shfl_down(s, off, 64);
        if (lane == 0) h1[n * 256 + j] = (float)s;
    }
}

// ---------------- fc2 ----------------
__global__ void fc2_kernel(const float* __restrict__ h1, const float* __restrict__ mean,
                           const float* __restrict__ rstd, const float* __restrict__ g,
                           const float* __restrict__ b, const float* __restrict__ ap,
                           const float* __restrict__ sfc2, float* __restrict__ h2) {
    int n = blockIdx.x;
    float a = ap[0];
    __shared__ float sv[256];
    int t = threadIdx.x;
    if (t < 256) {
        float v = h1[n * 256 + t];
        float bnv = (v - mean[t]) * rstd[t] * g[t] + b[t];
        float pr = bnv < 0.f ? a * bnv : bnv;
        sv[t] = fsign(pr);
    }
    __syncthreads();
    if (t < 64) {
        float s = 0.f;
        for (int k = 0; k < 256; ++k) s += sv[k] * sfc2[t * 256 + k];
        h2[n * 64 + t] = s;
    }
}

// ---------------- fc3 ----------------
__global__ void fc3_kernel(const float* __restrict__ h2, const float* __restrict__ mean,
                           const float* __restrict__ rstd, const float* __restrict__ g,
                           const float* __restrict__ b, const float* __restrict__ ap,
                           const float* __restrict__ sfc3, float* __restrict__ out) {
    int n = blockIdx.x;
    float a = ap[0];
    __shared__ float sv[64];
    int t = threadIdx.x;
    if (t < 64) {
        float v = h2[n * 64 + t];
        float bnv = (v - mean[t]) * rstd[t] * g[t] + b[t];
        float pr = bnv < 0.f ? a * bnv : bnv;
        sv[t] = fsign(pr);
    }
    __syncthreads();
    if (t < 2) {
        float s = 0.f;
        for (int k = 0; k < 64; ++k) s += sv[k] * sfc3[t * 64 + k];
        out[n * 2 + t] = s;
    }
}

extern "C" void kernel_launch(void* const* d_in, const int* in_sizes, int n_in,
                              void* d_out, int out_size, void* d_ws, size_t ws_size,
                              hipStream_t stream) {
    const float* x = (const float*)d_in[0];
    // dict order: 0:x, 1-10:w1..w10, stage i: g=11+3(i-1), b=12+3(i-1), a=13+3(i-1)
    // 26:fc1, 27:fc2, 28:fc3, 29:g6, 30:b6, 31:g7, 32:b7, 33:a6, 34:a7
    const float* G[8] = {nullptr, (const float*)d_in[11], (const float*)d_in[14],
                         (const float*)d_in[17], (const float*)d_in[20], (const float*)d_in[23],
                         (const float*)d_in[29], (const float*)d_in[31]};
    const float* B[8] = {nullptr, (const float*)d_in[12], (const float*)d_in[15],
                         (const float*)d_in[18], (const float*)d_in[21], (const float*)d_in[24],
                         (const float*)d_in[30], (const float*)d_in[32]};
    const float* A[8] = {nullptr, (const float*)d_in[13], (const float*)d_in[16],
                         (const float*)d_in[19], (const float*)d_in[22], (const float*)d_in[25],
                         (const float*)d_in[33], (const float*)d_in[34]};

    float* ws = (float*)d_ws;
    size_t off = 0;
    const int fsz[5] = {80, 1280, 262144, 16384, 128};
    float* fw[5];
    for (int i = 0; i < 5; ++i) { fw[i] = ws + off; off += (size_t)fsz[i]; }
    float* sw1 = fw[0]; float* sw2 = fw[1]; float* sfc1 = fw[2]; float* sfc2 = fw[3]; float* sfc3 = fw[4];

    const int psz[8] = {160, 160, 704, 1408, 768, 1536, 3072, 6144};
    unsigned* pn[8]; unsigned* pg[8];
    for (int i = 0; i < 8; ++i) {
        pn[i] = (unsigned*)(ws + off); off += (size_t)psz[i];
        pg[i] = (unsigned*)(ws + off); off += (size_t)psz[i];
    }

    float* p1 = ws + off; off += 16220160;   // 512*16*220*9
    float* p2 = ws + off; off += 6488064;    // 512*32*44*9
    float* p3 = ws + off; off += 1179648;    // 512*64*4*9
    float* p4 = ws + off; off += 786432;     // 512*128*4*3
    float* p5 = ws + off; off += 524288;     // 512*1024
    float* h1 = ws + off; off += 131072;     // 512*256
    float* h2 = ws + off; off += 32768;      // 512*64
    float* mean1 = ws + off; off += 16;  float* rstd1 = ws + off; off += 16;
    float* mean2 = ws + off; off += 32;  float* rstd2 = ws + off; off += 32;
    float* mean3 = ws + off; off += 64;  float* rstd3 = ws + off; off += 64;
    float* mean4 = ws + off; off += 128; float* rstd4 = ws + off; off += 128;
    float* mean5 = ws + off; off += 256; float* rstd5 = ws + off; off += 256;
    float* mean6 = ws + off; off += 256; float* rstd6 = ws + off; off += 256;
    float* mean7 = ws + off; off += 64;  float* rstd7 = ws + off; off += 64;
    if (off & 1) off += 1;  // 8B-align
    double* part = (double*)(ws + off); off += 2 * 16384;

    // 1. sign float-path weights
    WPtrs wp;
    const int fsrc_idx[5] = {1, 2, 26, 27, 28};
    for (int i = 0; i < 5; ++i) {
        wp.src[i] = (const float*)d_in[fsrc_idx[i]];
        wp.dst[i] = fw[i];
        wp.n[i] = fsz[i];
    }
    hipLaunchKernelGGL(sign_weights_kernel, dim3(32, 5), dim3(256), 0, stream, wp);

    // 2. pack conv weights w3..w10
    PWall pa;
    const int cout_[8] = {32, 32, 64, 64, 128, 128, 256, 256};
    const int cin_[8]  = {16, 32, 32, 64, 64, 128, 128, 256};
    const int kk_[8]   = {5, 5, 11, 11, 3, 3, 3, 3};
    for (int i = 0; i < 8; ++i) {
        pa.l[i].src = (const float*)d_in[3 + i];
        pa.l[i].dnz = pn[i];
        pa.l[i].dsg = pg[i];
        pa.l[i].cout = cout_[i];
        pa.l[i].cin = cin_[i];
        pa.l[i].k = kk_[i];
        pa.l[i].nw = (cin_[i] + 31) / 32;
    }
    hipLaunchKernelGGL(pack_weights_kernel, dim3(4, 8), dim3(256), 0, stream, pa);

    // 3. stage1 -> p1, stats
    hipLaunchKernelGGL(stage1_kernel, dim3(8, 512), dim3(256), 0, stream, x, sw1, sw2, p1);
    hipLaunchKernelGGL(stats_rows, dim3(16, 64), dim3(256), 0, stream, p1, 16, 512, 1980, 64, part);
    hipLaunchKernelGGL(stats_final, dim3(1), dim3(256), 0, stream, part, 16, 64, (long)512 * 1980, mean1, rstd1);

    // 4. stage2 -> p2, stats
    hipLaunchKernelGGL(stage2_kernel, dim3(11, 512), dim3(256), 0, stream, p1, mean1, rstd1,
                       G[1], B[1], A[1], pn[0], pg[0], pn[1], pg[1], p2);
    hipLaunchKernelGGL(stats_rows, dim3(32, 64), dim3(256), 0, stream, p2, 32, 512, 396, 64, part);
    hipLaunchKernelGGL(stats_final, dim3(1), dim3(256), 0, stream, part, 32, 64, (long)512 * 396, mean2, rstd2);

    // 5. stage3 -> p3, stats
    hipLaunchKernelGGL(stage3_kernel, dim3(4, 512), dim3(256), 0, stream, p2, mean2, rstd2,
                       G[2], B[2], A[2], pn[2], pg[2], pn[3], pg[3], p3);
    hipLaunchKernelGGL(stats_rows, dim3(64, 16), dim3(256), 0, stream, p3, 64, 512, 36, 16, part);
    hipLaunchKernelGGL(stats_final, dim3(1), dim3(256), 0, stream, part, 64, 16, (long)512 * 36, mean3, rstd3);

    // 6. stage4 -> p4, stats
    hipLaunchKernelGGL(stage4_kernel, dim3(4, 512), dim3(256), 0, stream, p3, mean3, rstd3,
                       G[3], B[3], A[3], pn[4], pg[4], pn[5], pg[5], p4);
    hipLaunchKernelGGL(stats_rows, dim3(128, 16), dim3(256), 0, stream, p4, 128, 512, 12, 16, part);
    hipLaunchKernelGGL(stats_final, dim3(1), dim3(256), 0, stream, part, 128, 16, (long)512 * 12, mean4, rstd4);

    // 7. stage5 -> p5, stats
    hipLaunchKernelGGL(stage5_kernel, dim3(4, 512), dim3(256), 0, stream, p4, mean4, rstd4,
                       G[4], B[4], A[4], pn[6], pg[6], pn[7], pg[7], p5);
    hipLaunchKernelGGL(stats_rows, dim3(256, 8), dim3(256), 0, stream, p5, 256, 512, 4, 8, part);
    hipLaunchKernelGGL(stats_final, dim3(1), dim3(256), 0, stream, part, 256, 8, (long)512 * 4, mean5, rstd5);

    // 8. fc1 -> h1, stats
    hipLaunchKernelGGL(fc1_kernel, dim3(512), dim3(256), 0, stream, p5, mean5, rstd5,
                       G[5], B[5], A[5], sfc1, h1);
    hipLaunchKernelGGL(stats_bn1d, dim3(256), dim3(64), 0, stream, h1, 256, 512, mean6, rstd6);

    // 9. fc2 -> h2, stats
    hipLaunchKernelGGL(fc2_kernel, dim3(512), dim3(256), 0, stream, h1, mean6, rstd6,
                       G[6], B[6], A[6], sfc2, h2);
    hipLaunchKernelGGL(stats_bn1d, dim3(64), dim3(64), 0, stream, h2, 64, 512, mean7, rstd7);

    // 10. fc3 -> d_out
    hipLaunchKernelGGL(fc3_kernel, dim3(512), dim3(256), 0, stream, h2, mean7, rstd7,
                       G[7], B[7], A[7], sfc3, (float*)d_out);
}

// Round 6
// 418.379 us; speedup vs baseline: 5.6121x; 1.2971x over previous
//
#include <hip/hip_runtime.h>
#include <hip/hip_bf16.h>

#define EPSV 1e-5

__device__ __forceinline__ float fsign(float x) {
    return (float)((x > 0.f) - (x < 0.f));
}

// ---------------- sign(weights) for float-path layers (w1, w2, fc1, fc2, fc3) ----------------
struct WPtrs {
    const float* src[5];
    float* dst[5];
    int n[5];
};

__global__ void sign_weights_kernel(WPtrs wp) {
    int wi = blockIdx.y;
    int n = wp.n[wi];
    const float* s = wp.src[wi];
    float* d = wp.dst[wi];
    for (int i = blockIdx.x * blockDim.x + threadIdx.x; i < n; i += gridDim.x * blockDim.x)
        d[i] = fsign(s[i]);
}

// ---------------- pack conv weights (w3..w10) along Cin into bit words ----------------
struct PW { const float* src; unsigned* dnz; unsigned* dsg; int cout, cin, k, nw; };
struct PWall { PW l[8]; };

__global__ void pack_weights_kernel(PWall pa) {
    PW p = pa.l[blockIdx.y];
    int total = p.cout * p.k * p.nw;
    for (int u = blockIdx.x * blockDim.x + threadIdx.x; u < total; u += gridDim.x * blockDim.x) {
        int co = u / (p.k * p.nw);
        int rem = u % (p.k * p.nw);
        int kk = rem / p.nw, wi = rem % p.nw;
        unsigned nz = 0, sg = 0;
        for (int j = 0; j < 32; ++j) {
            int ci = wi * 32 + j;
            if (ci < p.cin) {
                float v = p.src[(co * p.cin + ci) * p.k + kk];
                if (v != 0.f) nz |= 1u << j;
                if (v < 0.f) sg |= 1u << j;
            }
        }
        p.dnz[u] = nz;
        p.dsg[u] = sg;
    }
}

// ---------------- stage 1: conv1(f32) + conv2(fp64-accum), all-register a1 ----------------
__global__ void stage1_kernel(const float* __restrict__ x, const float* __restrict__ sw1,
                              const float* __restrict__ sw2, float* __restrict__ p1) {
    int n = blockIdx.y;
    int ho0 = blockIdx.x * 28;
    int nrows = min(28, 220 - ho0);
    int nrx = 5 * nrows + 4;
    __shared__ float xs[144 * 9];
    int t = threadIdx.x;
    int hbase = 5 * ho0 - 2;
    for (int i = t; i < nrx * 9; i += 256) {
        int r = i / 9, w = i - r * 9, h = hbase + r;
        xs[i] = (h >= 0 && h < 1100) ? x[(n * 1100 + h) * 9 + w] : 0.f;
    }
    __syncthreads();
    int npos = nrows * 9;
    if (t < npos) {
        int hoL = t / 9, w = t - hoL * 9;
        float xr[9];
        int base = 45 * hoL + w;
#pragma unroll
        for (int r = 0; r < 9; ++r) xr[r] = xs[base + 9 * r];
        double acc[16];
#pragma unroll
        for (int co = 0; co < 16; ++co) acc[co] = 0.0;
        for (int ci = 0; ci < 16; ++ci) {
            float a1k[5];
#pragma unroll
            for (int kh = 0; kh < 5; ++kh) {
                float s = 0.f;
#pragma unroll
                for (int k5 = 0; k5 < 5; ++k5) s += sw1[ci * 5 + k5] * xr[kh + k5];
                a1k[kh] = s;
            }
#pragma unroll
            for (int co = 0; co < 16; ++co) {
                const float* wrow = sw2 + (co * 16 + ci) * 5;
#pragma unroll
                for (int kh = 0; kh < 5; ++kh)
                    acc[co] += (double)(wrow[kh] * a1k[kh]);
            }
        }
        int ho = ho0 + hoL;
        long obase = ((long)n * 16) * 1980 + ho * 9 + w;
#pragma unroll
        for (int co = 0; co < 16; ++co)
            p1[obase + co * 1980] = (float)acc[co];
    }
}

// ---------------- BN partial stats, float4-vectorized, NCHW rows ----------------
__global__ void stats_rows(const float* __restrict__ x, int C, int N, int HW, int S,
                           double* __restrict__ part) {
    int c = blockIdx.x, s = blockIdx.y;
    int nlo = (int)((long)N * s / S), nhi = (int)((long)N * (s + 1) / S);
    unsigned HW4 = (unsigned)HW >> 2;
    unsigned tot = (unsigned)(nhi - nlo) * HW4;
    double sum = 0, sq = 0;
    for (unsigned u = threadIdx.x; u < tot; u += 256) {
        unsigned nn = u / HW4, j = u - nn * HW4;
        const float4 v = ((const float4*)(x + ((long)((nlo + nn) * C + c)) * HW))[j];
        sum += v.x; sq += (double)v.x * v.x;
        sum += v.y; sq += (double)v.y * v.y;
        sum += v.z; sq += (double)v.z * v.z;
        sum += v.w; sq += (double)v.w * v.w;
    }
    __shared__ double ls[256], lq[256];
    ls[threadIdx.x] = sum;
    lq[threadIdx.x] = sq;
    __syncthreads();
    for (int off = 128; off > 0; off >>= 1) {
        if ((int)threadIdx.x < off) {
            ls[threadIdx.x] += ls[threadIdx.x + off];
            lq[threadIdx.x] += lq[threadIdx.x + off];
        }
        __syncthreads();
    }
    if (threadIdx.x == 0) {
        part[(c * S + s) * 2] = ls[0];
        part[(c * S + s) * 2 + 1] = lq[0];
    }
}

__global__ void stats_final(const double* __restrict__ part, int C, int S, long count,
                            float* __restrict__ mean, float* __restrict__ rstd) {
    int c = blockIdx.x * blockDim.x + threadIdx.x;
    if (c >= C) return;
    double s = 0, q = 0;
    for (int i = 0; i < S; ++i) {
        s += part[(c * S + i) * 2];
        q += part[(c * S + i) * 2 + 1];
    }
    double m = s / (double)count;
    double v = q / (double)count - m * m;
    mean[c] = (float)m;
    rstd[c] = (float)(1.0 / sqrt(v + EPSV));
}

// ---------------- BN stats for bn1d (x[n*C + c]) ----------------
__global__ void stats_bn1d(const float* __restrict__ x, int C, int N,
                           float* __restrict__ mean, float* __restrict__ rstd) {
    int c = blockIdx.x;
    double sum = 0, sq = 0;
    for (int n = threadIdx.x; n < N; n += 64) {
        float v = x[(long)n * C + c];
        sum += v;
        sq += (double)v * v;
    }
    for (int off = 32; off > 0; off >>= 1) {
        sum += __shfl_down(sum, off);
        sq += __shfl_down(sq, off);
    }
    if (threadIdx.x == 0) {
        double m = sum / (double)N;
        double v = sq / (double)N - m * m;
        mean[c] = (float)m;
        rstd[c] = (float)(1.0 / sqrt(v + EPSV));
    }
}

// ---------------- stage 2: grid(11,512). LDS weights as uint2{nz,sg}, [kh][co] for conv3 ----------------
__global__ void stage2_kernel(const float* __restrict__ p1, const float* __restrict__ mean,
    const float* __restrict__ rstd, const float* __restrict__ g, const float* __restrict__ b,
    const float* __restrict__ ap, const unsigned* __restrict__ w3n, const unsigned* __restrict__ w3s,
    const unsigned* __restrict__ w4n, const unsigned* __restrict__ w4s, float* __restrict__ p2) {
    int hb = blockIdx.x;   // 0..10
    int n = blockIdx.y;
    float a = ap[0];
    __shared__ __align__(16) uint2 qx[216];         // p1 rows 20hb-2 .. 20hb+21
    __shared__ __align__(16) uint2 ax[180];         // conv3 rows 20hb .. 20hb+19
    __shared__ __align__(16) uint2 w3L[160];        // [kh*32+co]
    __shared__ __align__(16) uint2 w4L[160];        // [co*5+kh]
    int t = threadIdx.x;
    if (t < 160) {
        int kh = t / 32, co = t % 32;
        w3L[t] = make_uint2(w3n[co * 5 + kh], w3s[co * 5 + kh]);
        w4L[t] = make_uint2(w4n[t], w4s[t]);
    }
    if (t < 216) {
        int rl = t / 9, w = t % 9;
        int r = 20 * hb - 2 + rl;
        unsigned nz = 0, sg = 0;
        if (r >= 0 && r < 220) {
            for (int ci = 0; ci < 16; ++ci) {
                float v = p1[(n * 16 + ci) * 1980 + r * 9 + w];
                float bnv = (v - mean[ci]) * rstd[ci] * g[ci] + b[ci];
                float pr = bnv < 0.f ? a * bnv : bnv;
                if (pr != 0.f) { nz |= 1u << ci; if (pr < 0.f) sg |= 1u << ci; }
            }
        }
        qx[t] = make_uint2(nz, sg);
    }
    __syncthreads();
    // conv3: local rows jl 0..19, inputs local rows jl..jl+4
    if (t < 180) {
        int jl = t / 9, w = t % 9;
        uint2 xv[5];
#pragma unroll
        for (int kh = 0; kh < 5; ++kh) xv[kh] = qx[(jl + kh) * 9 + w];
        unsigned onz = 0, osg = 0;
        for (int co = 0; co < 32; co += 2) {
            int c0 = 0, n0 = 0, c1 = 0, n1 = 0;
#pragma unroll
            for (int kh = 0; kh < 5; ++kh) {
                const uint4 wv = *(const uint4*)&w3L[kh * 32 + co];
                unsigned b0 = xv[kh].x & wv.x;
                c0 += __popc(b0);
                n0 += __popc((xv[kh].y ^ wv.y) & b0);
                unsigned b1 = xv[kh].x & wv.z;
                c1 += __popc(b1);
                n1 += __popc((xv[kh].y ^ wv.w) & b1);
            }
            int s0 = c0 - 2 * n0, s1 = c1 - 2 * n1;
            if (s0 != 0) { onz |= 1u << co; if (s0 < 0) osg |= 1u << co; }
            if (s1 != 0) { onz |= 1u << (co + 1); if (s1 < 0) osg |= 1u << (co + 1); }
        }
        ax[t] = make_uint2(onz, osg);
    }
    __syncthreads();
    // conv4: rows 4hb..4hb+3, co 0..31, w 0..8 -> 1152 items
    for (int o = t; o < 1152; o += 256) {
        int co = o / 36, rem = o % 36, hol = rem / 9, w = rem % 9;
        int cnt = 0, neg = 0;
#pragma unroll
        for (int kh = 0; kh < 5; ++kh) {
            uint2 av = ax[(5 * hol + kh) * 9 + w];
            uint2 wv = w4L[co * 5 + kh];
            unsigned both = av.x & wv.x;
            cnt += __popc(both);
            neg += __popc((av.y ^ wv.y) & both);
        }
        p2[(n * 32 + co) * 396 + (4 * hb + hol) * 9 + w] = (float)(cnt - 2 * neg);
    }
}

// ---------------- stage 3: grid(4,512). LDS weights uint2; conv5 weights [kh][co] ----------------
__global__ void stage3_kernel(const float* __restrict__ p2, const float* __restrict__ mean,
    const float* __restrict__ rstd, const float* __restrict__ g, const float* __restrict__ b,
    const float* __restrict__ ap, const unsigned* __restrict__ w5n, const unsigned* __restrict__ w5s,
    const unsigned* __restrict__ w6n, const unsigned* __restrict__ w6s, float* __restrict__ p3) {
    int ho = blockIdx.x;   // 0..3
    int n = blockIdx.y;
    float a = ap[0];
    __shared__ __align__(16) uint2 qx[189];          // p2 rows 11ho-5 .. 11ho+15
    __shared__ __align__(16) uint2 ax[99 * 2];       // conv5 out [p*2+wi]
    __shared__ __align__(16) uint2 w5L[704];         // [kh*64+co]
    __shared__ __align__(16) uint2 w6L[1408];        // [(co*11+kh)*2+wi]
    int t = threadIdx.x;
    for (int i = t; i < 704; i += 256) {
        int kh = i / 64, co = i % 64;
        w5L[i] = make_uint2(w5n[co * 11 + kh], w5s[co * 11 + kh]);
    }
    for (int i = t; i < 1408; i += 256)
        w6L[i] = make_uint2(w6n[i], w6s[i]);
    if (t < 189) {
        int rl = t / 9, w = t % 9;
        int r = 11 * ho - 5 + rl;
        unsigned nz = 0, sg = 0;
        if (r >= 0 && r < 44) {
            for (int ci = 0; ci < 32; ++ci) {
                float v = p2[(n * 32 + ci) * 396 + r * 9 + w];
                float bnv = (v - mean[ci]) * rstd[ci] * g[ci] + b[ci];
                float pr = bnv < 0.f ? a * bnv : bnv;
                if (pr != 0.f) { nz |= 1u << ci; if (pr < 0.f) sg |= 1u << ci; }
            }
        }
        qx[t] = make_uint2(nz, sg);
    }
    __syncthreads();
    // conv5: local rows jl 0..10, inputs local rows jl..jl+10; unit = (p, wi)
    if (t < 198) {
        int p = t >> 1, wi = t & 1;
        int jl = p / 9, w = p % 9;
        uint2 xv[11];
#pragma unroll
        for (int kh = 0; kh < 11; ++kh) xv[kh] = qx[(jl + kh) * 9 + w];
        unsigned onz = 0, osg = 0;
        for (int jj = 0; jj < 32; jj += 2) {
            int co0 = wi * 32 + jj;
            int c0 = 0, n0 = 0, c1 = 0, n1 = 0;
#pragma unroll
            for (int kh = 0; kh < 11; ++kh) {
                const uint4 wv = *(const uint4*)&w5L[kh * 64 + co0];
                unsigned b0 = xv[kh].x & wv.x;
                c0 += __popc(b0);
                n0 += __popc((xv[kh].y ^ wv.y) & b0);
                unsigned b1 = xv[kh].x & wv.z;
                c1 += __popc(b1);
                n1 += __popc((xv[kh].y ^ wv.w) & b1);
            }
            int s0 = c0 - 2 * n0, s1 = c1 - 2 * n1;
            if (s0 != 0) { onz |= 1u << jj; if (s0 < 0) osg |= 1u << jj; }
            if (s1 != 0) { onz |= 1u << (jj + 1); if (s1 < 0) osg |= 1u << (jj + 1); }
        }
        ax[p * 2 + wi] = make_uint2(onz, osg);
    }
    __syncthreads();
    // conv6: co 0..63, w 0..8 -> 576 items; conv5 local row = kh
    for (int o = t; o < 576; o += 256) {
        int co = o / 9, w = o % 9;
        int cA = 0, nA = 0, cB = 0, nB = 0;
        for (int kh = 0; kh < 11; ++kh) {
            const uint4 av = *(const uint4*)&ax[(kh * 9 + w) * 2];
            const uint4 wv = *(const uint4*)&w6L[(co * 11 + kh) * 2];
            unsigned b0 = av.x & wv.x;
            cA += __popc(b0);
            nA += __popc((av.y ^ wv.y) & b0);
            unsigned b1 = av.z & wv.z;
            cB += __popc(b1);
            nB += __popc((av.w ^ wv.w) & b1);
        }
        p3[(n * 64 + co) * 36 + ho * 9 + w] = (float)((cA + cB) - 2 * (nA + nB));
    }
}

// ---------------- stage 4: grid(4,512): one h-row per block ----------------
__global__ void stage4_kernel(const float* __restrict__ p3, const float* __restrict__ mean,
    const float* __restrict__ rstd, const float* __restrict__ g, const float* __restrict__ b,
    const float* __restrict__ ap, const unsigned* __restrict__ w7n, const unsigned* __restrict__ w7s,
    const unsigned* __restrict__ w8n, const unsigned* __restrict__ w8s, float* __restrict__ p4) {
    int h = blockIdx.x;   // 0..3
    int n = blockIdx.y;
    float a = ap[0];
    __shared__ unsigned q[9 * 4];      // [w][nz0,nz1,sg0,sg1]
    __shared__ signed char strit[9 * 128];
    __shared__ unsigned an[9 * 4], ag[9 * 4];
    int t = threadIdx.x;
    if (t < 18) {
        int w = t >> 1, half = t & 1;
        unsigned nz = 0, sg = 0;
        for (int j = 0; j < 32; ++j) {
            int ci = half * 32 + j;
            float v = p3[(n * 64 + ci) * 36 + h * 9 + w];
            float bnv = (v - mean[ci]) * rstd[ci] * g[ci] + b[ci];
            float pr = bnv < 0.f ? a * bnv : bnv;
            if (pr != 0.f) { nz |= 1u << j; if (pr < 0.f) sg |= 1u << j; }
        }
        q[w * 4 + half] = nz; q[w * 4 + 2 + half] = sg;
    }
    __syncthreads();
    // conv7 per (w, co): 9*128 = 1152 items
    for (int o = t; o < 1152; o += 256) {
        int w = o / 128, co = o % 128;
        int cnt = 0, neg = 0;
        for (int kw = 0; kw < 3; ++kw) {
            int wl = w + kw - 1;
            if (wl < 0 || wl >= 9) continue;
#pragma unroll
            for (int iw = 0; iw < 2; ++iw) {
                unsigned both = q[wl * 4 + iw] & w7n[(co * 3 + kw) * 2 + iw];
                cnt += __popc(both);
                neg += __popc((q[wl * 4 + 2 + iw] ^ w7s[(co * 3 + kw) * 2 + iw]) & both);
            }
        }
        int s = cnt - 2 * neg;
        strit[o] = (signed char)((s > 0) - (s < 0));
    }
    __syncthreads();
    if (t < 36) {
        int w = t >> 2, wi = t & 3;
        unsigned nz = 0, sg = 0;
        for (int j = 0; j < 32; ++j) {
            int tr = strit[w * 128 + wi * 32 + j];
            if (tr) { nz |= 1u << j; if (tr < 0) sg |= 1u << j; }
        }
        an[w * 4 + wi] = nz; ag[w * 4 + wi] = sg;
    }
    __syncthreads();
    // conv8 per (co, wo): 128*3 = 384 items
    for (int o = t; o < 384; o += 256) {
        int co = o / 3, wo = o % 3;
        int cnt = 0, neg = 0;
        for (int kw = 0; kw < 3; ++kw) {
            int wl = 3 * wo + kw;
#pragma unroll
            for (int iw = 0; iw < 4; ++iw) {
                unsigned both = an[wl * 4 + iw] & w8n[(co * 3 + kw) * 4 + iw];
                cnt += __popc(both);
                neg += __popc((ag[wl * 4 + iw] ^ w8s[(co * 3 + kw) * 4 + iw]) & both);
            }
        }
        p4[(n * 128 + co) * 12 + h * 3 + wo] = (float)(cnt - 2 * neg);
    }
}

// ---------------- stage 5: grid(4,512): one h-row per block ----------------
__global__ void stage5_kernel(const float* __restrict__ p4, const float* __restrict__ mean,
    const float* __restrict__ rstd, const float* __restrict__ g, const float* __restrict__ b,
    const float* __restrict__ ap, const unsigned* __restrict__ w9n, const unsigned* __restrict__ w9s,
    const unsigned* __restrict__ w10n, const unsigned* __restrict__ w10s, float* __restrict__ p5) {
    int h = blockIdx.x;   // 0..3
    int n = blockIdx.y;
    float a = ap[0];
    __shared__ unsigned q[3 * 8];      // [w][nz0..3, sg0..3]
    __shared__ signed char strit[3 * 256];
    __shared__ unsigned an[3 * 8], ag[3 * 8];
    int t = threadIdx.x;
    if (t < 12) {
        int w = t >> 2, wq = t & 3;
        unsigned nz = 0, sg = 0;
        for (int j = 0; j < 32; ++j) {
            int ci = wq * 32 + j;
            float v = p4[(n * 128 + ci) * 12 + h * 3 + w];
            float bnv = (v - mean[ci]) * rstd[ci] * g[ci] + b[ci];
            float pr = bnv < 0.f ? a * bnv : bnv;
            if (pr != 0.f) { nz |= 1u << j; if (pr < 0.f) sg |= 1u << j; }
        }
        q[w * 8 + wq] = nz; q[w * 8 + 4 + wq] = sg;
    }
    __syncthreads();
    // conv9 per (w, co): 3*256 = 768 items
    for (int o = t; o < 768; o += 256) {
        int w = o / 256, co = o % 256;
        int cnt = 0, neg = 0;
        for (int kw = 0; kw < 3; ++kw) {
            int wl = w + kw - 1;
            if (wl < 0 || wl >= 3) continue;
#pragma unroll
            for (int iw = 0; iw < 4; ++iw) {
                unsigned both = q[wl * 8 + iw] & w9n[(co * 3 + kw) * 4 + iw];
                cnt += __popc(both);
                neg += __popc((q[wl * 8 + 4 + iw] ^ w9s[(co * 3 + kw) * 4 + iw]) & both);
            }
        }
        int s = cnt - 2 * neg;
        strit[o] = (signed char)((s > 0) - (s < 0));
    }
    __syncthreads();
    if (t < 24) {
        int w = t >> 3, wi = t & 7;
        unsigned nz = 0, sg = 0;
        for (int j = 0; j < 32; ++j) {
            int tr = strit[w * 256 + wi * 32 + j];
            if (tr) { nz |= 1u << j; if (tr < 0) sg |= 1u << j; }
        }
        an[w * 8 + wi] = nz; ag[w * 8 + wi] = sg;
    }
    __syncthreads();
    // conv10 per co: 256 items
    if (t < 256) {
        int co = t;
        int cnt = 0, neg = 0;
        for (int kw = 0; kw < 3; ++kw) {
#pragma unroll
            for (int iw = 0; iw < 8; ++iw) {
                unsigned both = an[kw * 8 + iw] & w10n[(co * 3 + kw) * 8 + iw];
                cnt += __popc(both);
                neg += __popc((ag[kw * 8 + iw] ^ w10s[(co * 3 + kw) * 8 + iw]) & both);
            }
        }
        p5[n * 1024 + co * 4 + h] = (float)(cnt - 2 * neg);
    }
}

// ---------------- fc1: prelu(bn2d(p5)) @ sign(fc1).T, wave-per-output ----------------
__global__ void fc1_kernel(const float* __restrict__ p5, const float* __restrict__ mean,
                           const float* __restrict__ rstd, const float* __restrict__ g,
                           const float* __restrict__ b, const float* __restrict__ ap,
                           const float* __restrict__ sfc1, float* __restrict__ h1) {
    int n = blockIdx.x;
    float a = ap[0];
    __shared__ float hv[1024];
    int t = threadIdx.x;
    for (int idx = t; idx < 1024; idx += 256) {
        int c = idx >> 2;
        float v = p5[n * 1024 + idx];
        float bnv = (v - mean[c]) * rstd[c] * g[c] + b[c];
        hv[idx] = bnv < 0.f ? a * bnv : bnv;
    }
    __syncthreads();
    int wave = t >> 6, lane = t & 63;
    float hr[16];
#pragma unroll
    for (int m = 0; m < 16; ++m) hr[m] = hv[lane * 16 + m];
    for (int jj = 0; jj < 64; ++jj) {
        int j = wave * 64 + jj;
        const float4* wr = (const float4*)(sfc1 + (j << 10) + (lane << 4));
        double s = 0.0;
#pragma unroll
        for (int q4 = 0; q4 < 4; ++q4) {
            float4 wv = wr[q4];
            s += (double)(hr[q4 * 4 + 0] * wv.x);
            s += (double)(hr[q4 * 4 + 1] * wv.y);
            s += (double)(hr[q4 * 4 + 2] * wv.z);
            s += (double)(hr[q4 * 4 + 3] * wv.w);
        }
#pragma unroll
        for (int off = 32; off > 0; off >>= 1) s += __shfl_down(s, off, 64);
        if (lane == 0) h1[n * 256 + j] = (float)s;
    }
}

// ---------------- fc2 ----------------
__global__ void fc2_kernel(const float* __restrict__ h1, const float* __restrict__ mean,
                           const float* __restrict__ rstd, const float* __restrict__ g,
                           const float* __restrict__ b, const float* __restrict__ ap,
                           const float* __restrict__ sfc2, float* __restrict__ h2) {
    int n = blockIdx.x;
    float a = ap[0];
    __shared__ float sv[256];
    int t = threadIdx.x;
    if (t < 256) {
        float v = h1[n * 256 + t];
        float bnv = (v - mean[t]) * rstd[t] * g[t] + b[t];
        float pr = bnv < 0.f ? a * bnv : bnv;
        sv[t] = fsign(pr);
    }
    __syncthreads();
    if (t < 64) {
        float s = 0.f;
        for (int k = 0; k < 256; ++k) s += sv[k] * sfc2[t * 256 + k];
        h2[n * 64 + t] = s;
    }
}

// ---------------- fc3 ----------------
__global__ void fc3_kernel(const float* __restrict__ h2, const float* __restrict__ mean,
                           const float* __restrict__ rstd, const float* __restrict__ g,
                           const float* __restrict__ b, const float* __restrict__ ap,
                           const float* __restrict__ sfc3, float* __restrict__ out) {
    int n = blockIdx.x;
    float a = ap[0];
    __shared__ float sv[64];
    int t = threadIdx.x;
    if (t < 64) {
        float v = h2[n * 64 + t];
        float bnv = (v - mean[t]) * rstd[t] * g[t] + b[t];
        float pr = bnv < 0.f ? a * bnv : bnv;
        sv[t] = fsign(pr);
    }
    __syncthreads();
    if (t < 2) {
        float s = 0.f;
        for (int k = 0; k < 64; ++k) s += sv[k] * sfc3[t * 64 + k];
        out[n * 2 + t] = s;
    }
}

extern "C" void kernel_launch(void* const* d_in, const int* in_sizes, int n_in,
                              void* d_out, int out_size, void* d_ws, size_t ws_size,
                              hipStream_t stream) {
    const float* x = (const float*)d_in[0];
    // dict order: 0:x, 1-10:w1..w10, stage i: g=11+3(i-1), b=12+3(i-1), a=13+3(i-1)
    // 26:fc1, 27:fc2, 28:fc3, 29:g6, 30:b6, 31:g7, 32:b7, 33:a6, 34:a7
    const float* G[8] = {nullptr, (const float*)d_in[11], (const float*)d_in[14],
                         (const float*)d_in[17], (const float*)d_in[20], (const float*)d_in[23],
                         (const float*)d_in[29], (const float*)d_in[31]};
    const float* B[8] = {nullptr, (const float*)d_in[12], (const float*)d_in[15],
                         (const float*)d_in[18], (const float*)d_in[21], (const float*)d_in[24],
                         (const float*)d_in[30], (const float*)d_in[32]};
    const float* A[8] = {nullptr, (const float*)d_in[13], (const float*)d_in[16],
                         (const float*)d_in[19], (const float*)d_in[22], (const float*)d_in[25],
                         (const float*)d_in[33], (const float*)d_in[34]};

    float* ws = (float*)d_ws;
    size_t off = 0;
    const int fsz[5] = {80, 1280, 262144, 16384, 128};
    float* fw[5];
    for (int i = 0; i < 5; ++i) { fw[i] = ws + off; off += (size_t)fsz[i]; }
    float* sw1 = fw[0]; float* sw2 = fw[1]; float* sfc1 = fw[2]; float* sfc2 = fw[3]; float* sfc3 = fw[4];

    const int psz[8] = {160, 160, 704, 1408, 768, 1536, 3072, 6144};
    unsigned* pn[8]; unsigned* pg[8];
    for (int i = 0; i < 8; ++i) {
        pn[i] = (unsigned*)(ws + off); off += (size_t)psz[i];
        pg[i] = (unsigned*)(ws + off); off += (size_t)psz[i];
    }

    float* p1 = ws + off; off += 16220160;   // 512*16*220*9
    float* p2 = ws + off; off += 6488064;    // 512*32*44*9
    float* p3 = ws + off; off += 1179648;    // 512*64*4*9
    float* p4 = ws + off; off += 786432;     // 512*128*4*3
    float* p5 = ws + off; off += 524288;     // 512*1024
    float* h1 = ws + off; off += 131072;     // 512*256
    float* h2 = ws + off; off += 32768;      // 512*64
    float* mean1 = ws + off; off += 16;  float* rstd1 = ws + off; off += 16;
    float* mean2 = ws + off; off += 32;  float* rstd2 = ws + off; off += 32;
    float* mean3 = ws + off; off += 64;  float* rstd3 = ws + off; off += 64;
    float* mean4 = ws + off; off += 128; float* rstd4 = ws + off; off += 128;
    float* mean5 = ws + off; off += 256; float* rstd5 = ws + off; off += 256;
    float* mean6 = ws + off; off += 256; float* rstd6 = ws + off; off += 256;
    float* mean7 = ws + off; off += 64;  float* rstd7 = ws + off; off += 64;
    if (off & 1) off += 1;  // 8B-align
    double* part = (double*)(ws + off); off += 2 * 16384;

    // 1. sign float-path weights
    WPtrs wp;
    const int fsrc_idx[5] = {1, 2, 26, 27, 28};
    for (int i = 0; i < 5; ++i) {
        wp.src[i] = (const float*)d_in[fsrc_idx[i]];
        wp.dst[i] = fw[i];
        wp.n[i] = fsz[i];
    }
    hipLaunchKernelGGL(sign_weights_kernel, dim3(32, 5), dim3(256), 0, stream, wp);

    // 2. pack conv weights w3..w10
    PWall pa;
    const int cout_[8] = {32, 32, 64, 64, 128, 128, 256, 256};
    const int cin_[8]  = {16, 32, 32, 64, 64, 128, 128, 256};
    const int kk_[8]   = {5, 5, 11, 11, 3, 3, 3, 3};
    for (int i = 0; i < 8; ++i) {
        pa.l[i].src = (const float*)d_in[3 + i];
        pa.l[i].dnz = pn[i];
        pa.l[i].dsg = pg[i];
        pa.l[i].cout = cout_[i];
        pa.l[i].cin = cin_[i];
        pa.l[i].k = kk_[i];
        pa.l[i].nw = (cin_[i] + 31) / 32;
    }
    hipLaunchKernelGGL(pack_weights_kernel, dim3(4, 8), dim3(256), 0, stream, pa);

    // 3. stage1 -> p1, stats
    hipLaunchKernelGGL(stage1_kernel, dim3(8, 512), dim3(256), 0, stream, x, sw1, sw2, p1);
    hipLaunchKernelGGL(stats_rows, dim3(16, 64), dim3(256), 0, stream, p1, 16, 512, 1980, 64, part);
    hipLaunchKernelGGL(stats_final, dim3(1), dim3(256), 0, stream, part, 16, 64, (long)512 * 1980, mean1, rstd1);

    // 4. stage2 -> p2, stats
    hipLaunchKernelGGL(stage2_kernel, dim3(11, 512), dim3(256), 0, stream, p1, mean1, rstd1,
                       G[1], B[1], A[1], pn[0], pg[0], pn[1], pg[1], p2);
    hipLaunchKernelGGL(stats_rows, dim3(32, 64), dim3(256), 0, stream, p2, 32, 512, 396, 64, part);
    hipLaunchKernelGGL(stats_final, dim3(1), dim3(256), 0, stream, part, 32, 64, (long)512 * 396, mean2, rstd2);

    // 5. stage3 -> p3, stats
    hipLaunchKernelGGL(stage3_kernel, dim3(4, 512), dim3(256), 0, stream, p2, mean2, rstd2,
                       G[2], B[2], A[2], pn[2], pg[2], pn[3], pg[3], p3);
    hipLaunchKernelGGL(stats_rows, dim3(64, 16), dim3(256), 0, stream, p3, 64, 512, 36, 16, part);
    hipLaunchKernelGGL(stats_final, dim3(1), dim3(256), 0, stream, part, 64, 16, (long)512 * 36, mean3, rstd3);

    // 6. stage4 -> p4, stats
    hipLaunchKernelGGL(stage4_kernel, dim3(4, 512), dim3(256), 0, stream, p3, mean3, rstd3,
                       G[3], B[3], A[3], pn[4], pg[4], pn[5], pg[5], p4);
    hipLaunchKernelGGL(stats_rows, dim3(128, 16), dim3(256), 0, stream, p4, 128, 512, 12, 16, part);
    hipLaunchKernelGGL(stats_final, dim3(1), dim3(256), 0, stream, part, 128, 16, (long)512 * 12, mean4, rstd4);

    // 7. stage5 -> p5, stats
    hipLaunchKernelGGL(stage5_kernel, dim3(4, 512), dim3(256), 0, stream, p4, mean4, rstd4,
                       G[4], B[4], A[4], pn[6], pg[6], pn[7], pg[7], p5);
    hipLaunchKernelGGL(stats_rows, dim3(256, 8), dim3(256), 0, stream, p5, 256, 512, 4, 8, part);
    hipLaunchKernelGGL(stats_final, dim3(1), dim3(256), 0, stream, part, 256, 8, (long)512 * 4, mean5, rstd5);

    // 8. fc1 -> h1, stats
    hipLaunchKernelGGL(fc1_kernel, dim3(512), dim3(256), 0, stream, p5, mean5, rstd5,
                       G[5], B[5], A[5], sfc1, h1);
    hipLaunchKernelGGL(stats_bn1d, dim3(256), dim3(64), 0, stream, h1, 256, 512, mean6, rstd6);

    // 9. fc2 -> h2, stats
    hipLaunchKernelGGL(fc2_kernel, dim3(512), dim3(256), 0, stream, h1, mean6, rstd6,
                       G[6], B[6], A[6], sfc2, h2);
    hipLaunchKernelGGL(stats_bn1d, dim3(64), dim3(64), 0, stream, h2, 64, 512, mean7, rstd7);

    // 10. fc3 -> d_out
    hipLaunchKernelGGL(fc3_kernel, dim3(512), dim3(256), 0, stream, h2, mean7, rstd7,
                       G[7], B[7], A[7], sfc3, (float*)d_out);
}

// Round 7
// 332.089 us; speedup vs baseline: 7.0704x; 1.2598x over previous
//
#include <hip/hip_runtime.h>
#include <hip/hip_bf16.h>

#define EPSV 1e-5

__device__ __forceinline__ float fsign(float x) {
    return (float)((x > 0.f) - (x < 0.f));
}

// ---------------- sign(weights) for fc1, fc2, fc3 ----------------
struct WPtrs {
    const float* src[3];
    float* dst[3];
    int n[3];
};

__global__ void sign_weights_kernel(WPtrs wp) {
    int wi = blockIdx.y;
    int n = wp.n[wi];
    const float* s = wp.src[wi];
    float* d = wp.dst[wi];
    for (int i = blockIdx.x * blockDim.x + threadIdx.x; i < n; i += gridDim.x * blockDim.x)
        d[i] = fsign(s[i]);
}

// ---------------- composite stage1 weights: Wc[co][r] = sum_{kh+k5=r} sign(w2)·sign(w1), integer ----------------
__global__ void build_wc_kernel(const float* __restrict__ w1, const float* __restrict__ w2,
                                float* __restrict__ wc) {
    int t = threadIdx.x;
    if (t < 208) {
        int co = t / 13, r = t % 13;
        float s = 0.f;
        for (int ci = 0; ci < 16; ++ci)
#pragma unroll
            for (int kh = 0; kh < 5; ++kh) {
                int k5 = r - kh;
                if (k5 >= 0 && k5 < 5)
                    s += fsign(w2[(co * 16 + ci) * 5 + kh]) * fsign(w1[ci * 5 + k5]);
            }
        wc[t] = s;  // exact integer
    }
}

// ---------------- pack conv weights (w3..w10) along Cin into bit words ----------------
struct PW { const float* src; unsigned* dnz; unsigned* dsg; int cout, cin, k, nw; };
struct PWall { PW l[8]; };

__global__ void pack_weights_kernel(PWall pa) {
    PW p = pa.l[blockIdx.y];
    int total = p.cout * p.k * p.nw;
    for (int u = blockIdx.x * blockDim.x + threadIdx.x; u < total; u += gridDim.x * blockDim.x) {
        int co = u / (p.k * p.nw);
        int rem = u % (p.k * p.nw);
        int kk = rem / p.nw, wi = rem % p.nw;
        unsigned nz = 0, sg = 0;
        for (int j = 0; j < 32; ++j) {
            int ci = wi * 32 + j;
            if (ci < p.cin) {
                float v = p.src[(co * p.cin + ci) * p.k + kk];
                if (v != 0.f) nz |= 1u << j;
                if (v < 0.f) sg |= 1u << j;
            }
        }
        p.dnz[u] = nz;
        p.dsg[u] = sg;
    }
}

// ---------------- stage 1: single 13-tap composite conv, integer weights, f64 accum (exact) ----------------
// x (512,1,1100,9) -> p1 (512,16,220,9). grid (8, 512): 28 output rows per block.
__global__ void stage1_kernel(const float* __restrict__ x, const float* __restrict__ wcg,
                              float* __restrict__ p1) {
    int n = blockIdx.y;
    int ho0 = blockIdx.x * 28;
    int nrows = min(28, 220 - ho0);
    int nrx = 5 * nrows + 8;            // rows 5*ho0-2 .. 5*ho0+5*nrows+5
    __shared__ float xs[148 * 9];
    __shared__ float wcl[208];
    int t = threadIdx.x;
    if (t < 208) wcl[t] = wcg[t];
    int hbase = 5 * ho0 - 2;
    for (int i = t; i < nrx * 9; i += 256) {
        int r = i / 9, w = i - r * 9, h = hbase + r;
        xs[i] = (h >= 0 && h < 1100) ? x[(n * 1100 + h) * 9 + w] : 0.f;
    }
    __syncthreads();
    int npos = nrows * 9;
    if (t < npos) {
        int hoL = t / 9, w = t - hoL * 9;
        double xr[13];
        int base = 45 * hoL + w;
#pragma unroll
        for (int r = 0; r < 13; ++r) xr[r] = (double)xs[base + 9 * r];
        int ho = ho0 + hoL;
        long obase = ((long)n * 16) * 1980 + ho * 9 + w;
#pragma unroll
        for (int co = 0; co < 16; ++co) {
            double acc = 0.0;
#pragma unroll
            for (int r = 0; r < 13; ++r)
                acc += (double)wcl[co * 13 + r] * xr[r];
            p1[obase + co * 1980] = (float)acc;
        }
    }
}

// ---------------- BN partial stats, float4-vectorized, NCHW rows ----------------
__global__ void stats_rows(const float* __restrict__ x, int C, int N, int HW, int S,
                           double* __restrict__ part) {
    int c = blockIdx.x, s = blockIdx.y;
    int nlo = (int)((long)N * s / S), nhi = (int)((long)N * (s + 1) / S);
    unsigned HW4 = (unsigned)HW >> 2;
    unsigned tot = (unsigned)(nhi - nlo) * HW4;
    double sum = 0, sq = 0;
    for (unsigned u = threadIdx.x; u < tot; u += 256) {
        unsigned nn = u / HW4, j = u - nn * HW4;
        const float4 v = ((const float4*)(x + ((long)((nlo + nn) * C + c)) * HW))[j];
        sum += v.x; sq += (double)v.x * v.x;
        sum += v.y; sq += (double)v.y * v.y;
        sum += v.z; sq += (double)v.z * v.z;
        sum += v.w; sq += (double)v.w * v.w;
    }
    __shared__ double ls[256], lq[256];
    ls[threadIdx.x] = sum;
    lq[threadIdx.x] = sq;
    __syncthreads();
    for (int off = 128; off > 0; off >>= 1) {
        if ((int)threadIdx.x < off) {
            ls[threadIdx.x] += ls[threadIdx.x + off];
            lq[threadIdx.x] += lq[threadIdx.x + off];
        }
        __syncthreads();
    }
    if (threadIdx.x == 0) {
        part[(c * S + s) * 2] = ls[0];
        part[(c * S + s) * 2 + 1] = lq[0];
    }
}

__global__ void stats_final(const double* __restrict__ part, int C, int S, long count,
                            float* __restrict__ mean, float* __restrict__ rstd) {
    int c = blockIdx.x * blockDim.x + threadIdx.x;
    if (c >= C) return;
    double s = 0, q = 0;
    for (int i = 0; i < S; ++i) {
        s += part[(c * S + i) * 2];
        q += part[(c * S + i) * 2 + 1];
    }
    double m = s / (double)count;
    double v = q / (double)count - m * m;
    mean[c] = (float)m;
    rstd[c] = (float)(1.0 / sqrt(v + EPSV));
}

// ---------------- BN stats for bn1d (x[n*C + c]) ----------------
__global__ void stats_bn1d(const float* __restrict__ x, int C, int N,
                           float* __restrict__ mean, float* __restrict__ rstd) {
    int c = blockIdx.x;
    double sum = 0, sq = 0;
    for (int n = threadIdx.x; n < N; n += 64) {
        float v = x[(long)n * C + c];
        sum += v;
        sq += (double)v * v;
    }
    for (int off = 32; off > 0; off >>= 1) {
        sum += __shfl_down(sum, off);
        sq += __shfl_down(sq, off);
    }
    if (threadIdx.x == 0) {
        double m = sum / (double)N;
        double v = sq / (double)N - m * m;
        mean[c] = (float)m;
        rstd[c] = (float)(1.0 / sqrt(v + EPSV));
    }
}

// ---------------- stage 2: grid(11,512). LDS weights as uint2{nz,sg}, [kh][co] for conv3 ----------------
__global__ void stage2_kernel(const float* __restrict__ p1, const float* __restrict__ mean,
    const float* __restrict__ rstd, const float* __restrict__ g, const float* __restrict__ b,
    const float* __restrict__ ap, const unsigned* __restrict__ w3n, const unsigned* __restrict__ w3s,
    const unsigned* __restrict__ w4n, const unsigned* __restrict__ w4s, float* __restrict__ p2) {
    int hb = blockIdx.x;   // 0..10
    int n = blockIdx.y;
    float a = ap[0];
    __shared__ __align__(16) uint2 qx[216];         // p1 rows 20hb-2 .. 20hb+21
    __shared__ __align__(16) uint2 ax[180];         // conv3 rows 20hb .. 20hb+19
    __shared__ __align__(16) uint2 w3L[160];        // [kh*32+co]
    __shared__ __align__(16) uint2 w4L[160];        // [co*5+kh]
    int t = threadIdx.x;
    if (t < 160) {
        int kh = t / 32, co = t % 32;
        w3L[t] = make_uint2(w3n[co * 5 + kh], w3s[co * 5 + kh]);
        w4L[t] = make_uint2(w4n[t], w4s[t]);
    }
    if (t < 216) {
        int rl = t / 9, w = t % 9;
        int r = 20 * hb - 2 + rl;
        unsigned nz = 0, sg = 0;
        if (r >= 0 && r < 220) {
            for (int ci = 0; ci < 16; ++ci) {
                float v = p1[(n * 16 + ci) * 1980 + r * 9 + w];
                float bnv = (v - mean[ci]) * rstd[ci] * g[ci] + b[ci];
                float pr = bnv < 0.f ? a * bnv : bnv;
                if (pr != 0.f) { nz |= 1u << ci; if (pr < 0.f) sg |= 1u << ci; }
            }
        }
        qx[t] = make_uint2(nz, sg);
    }
    __syncthreads();
    // conv3: local rows jl 0..19, inputs local rows jl..jl+4
    if (t < 180) {
        int jl = t / 9, w = t % 9;
        uint2 xv[5];
#pragma unroll
        for (int kh = 0; kh < 5; ++kh) xv[kh] = qx[(jl + kh) * 9 + w];
        unsigned onz = 0, osg = 0;
        for (int co = 0; co < 32; co += 2) {
            int c0 = 0, n0 = 0, c1 = 0, n1 = 0;
#pragma unroll
            for (int kh = 0; kh < 5; ++kh) {
                const uint4 wv = *(const uint4*)&w3L[kh * 32 + co];
                unsigned b0 = xv[kh].x & wv.x;
                c0 += __popc(b0);
                n0 += __popc((xv[kh].y ^ wv.y) & b0);
                unsigned b1 = xv[kh].x & wv.z;
                c1 += __popc(b1);
                n1 += __popc((xv[kh].y ^ wv.w) & b1);
            }
            int s0 = c0 - 2 * n0, s1 = c1 - 2 * n1;
            if (s0 != 0) { onz |= 1u << co; if (s0 < 0) osg |= 1u << co; }
            if (s1 != 0) { onz |= 1u << (co + 1); if (s1 < 0) osg |= 1u << (co + 1); }
        }
        ax[t] = make_uint2(onz, osg);
    }
    __syncthreads();
    // conv4: rows 4hb..4hb+3, co 0..31, w 0..8 -> 1152 items
    for (int o = t; o < 1152; o += 256) {
        int co = o / 36, rem = o % 36, hol = rem / 9, w = rem % 9;
        int cnt = 0, neg = 0;
#pragma unroll
        for (int kh = 0; kh < 5; ++kh) {
            uint2 av = ax[(5 * hol + kh) * 9 + w];
            uint2 wv = w4L[co * 5 + kh];
            unsigned both = av.x & wv.x;
            cnt += __popc(both);
            neg += __popc((av.y ^ wv.y) & both);
        }
        p2[(n * 32 + co) * 396 + (4 * hb + hol) * 9 + w] = (float)(cnt - 2 * neg);
    }
}

// ---------------- stage 3: grid(4,512). LDS weights uint2; conv5 weights [kh][co] ----------------
__global__ void stage3_kernel(const float* __restrict__ p2, const float* __restrict__ mean,
    const float* __restrict__ rstd, const float* __restrict__ g, const float* __restrict__ b,
    const float* __restrict__ ap, const unsigned* __restrict__ w5n, const unsigned* __restrict__ w5s,
    const unsigned* __restrict__ w6n, const unsigned* __restrict__ w6s, float* __restrict__ p3) {
    int ho = blockIdx.x;   // 0..3
    int n = blockIdx.y;
    float a = ap[0];
    __shared__ __align__(16) uint2 qx[189];          // p2 rows 11ho-5 .. 11ho+15
    __shared__ __align__(16) uint2 ax[99 * 2];       // conv5 out [p*2+wi]
    __shared__ __align__(16) uint2 w5L[704];         // [kh*64+co]
    __shared__ __align__(16) uint2 w6L[1408];        // [(co*11+kh)*2+wi]
    int t = threadIdx.x;
    for (int i = t; i < 704; i += 256) {
        int kh = i / 64, co = i % 64;
        w5L[i] = make_uint2(w5n[co * 11 + kh], w5s[co * 11 + kh]);
    }
    for (int i = t; i < 1408; i += 256)
        w6L[i] = make_uint2(w6n[i], w6s[i]);
    if (t < 189) {
        int rl = t / 9, w = t % 9;
        int r = 11 * ho - 5 + rl;
        unsigned nz = 0, sg = 0;
        if (r >= 0 && r < 44) {
            for (int ci = 0; ci < 32; ++ci) {
                float v = p2[(n * 32 + ci) * 396 + r * 9 + w];
                float bnv = (v - mean[ci]) * rstd[ci] * g[ci] + b[ci];
                float pr = bnv < 0.f ? a * bnv : bnv;
                if (pr != 0.f) { nz |= 1u << ci; if (pr < 0.f) sg |= 1u << ci; }
            }
        }
        qx[t] = make_uint2(nz, sg);
    }
    __syncthreads();
    // conv5: local rows jl 0..10, inputs local rows jl..jl+10; unit = (p, wi)
    if (t < 198) {
        int p = t >> 1, wi = t & 1;
        int jl = p / 9, w = p % 9;
        uint2 xv[11];
#pragma unroll
        for (int kh = 0; kh < 11; ++kh) xv[kh] = qx[(jl + kh) * 9 + w];
        unsigned onz = 0, osg = 0;
        for (int jj = 0; jj < 32; jj += 2) {
            int co0 = wi * 32 + jj;
            int c0 = 0, n0 = 0, c1 = 0, n1 = 0;
#pragma unroll
            for (int kh = 0; kh < 11; ++kh) {
                const uint4 wv = *(const uint4*)&w5L[kh * 64 + co0];
                unsigned b0 = xv[kh].x & wv.x;
                c0 += __popc(b0);
                n0 += __popc((xv[kh].y ^ wv.y) & b0);
                unsigned b1 = xv[kh].x & wv.z;
                c1 += __popc(b1);
                n1 += __popc((xv[kh].y ^ wv.w) & b1);
            }
            int s0 = c0 - 2 * n0, s1 = c1 - 2 * n1;
            if (s0 != 0) { onz |= 1u << jj; if (s0 < 0) osg |= 1u << jj; }
            if (s1 != 0) { onz |= 1u << (jj + 1); if (s1 < 0) osg |= 1u << (jj + 1); }
        }
        ax[p * 2 + wi] = make_uint2(onz, osg);
    }
    __syncthreads();
    // conv6: co 0..63, w 0..8 -> 576 items; conv5 local row = kh
    for (int o = t; o < 576; o += 256) {
        int co = o / 9, w = o % 9;
        int cA = 0, nA = 0, cB = 0, nB = 0;
        for (int kh = 0; kh < 11; ++kh) {
            const uint4 av = *(const uint4*)&ax[(kh * 9 + w) * 2];
            const uint4 wv = *(const uint4*)&w6L[(co * 11 + kh) * 2];
            unsigned b0 = av.x & wv.x;
            cA += __popc(b0);
            nA += __popc((av.y ^ wv.y) & b0);
            unsigned b1 = av.z & wv.z;
            cB += __popc(b1);
            nB += __popc((av.w ^ wv.w) & b1);
        }
        p3[(n * 64 + co) * 36 + ho * 9 + w] = (float)((cA + cB) - 2 * (nA + nB));
    }
}

// ---------------- stage 4: grid(4,512): one h-row per block ----------------
__global__ void stage4_kernel(const float* __restrict__ p3, const float* __restrict__ mean,
    const float* __restrict__ rstd, const float* __restrict__ g, const float* __restrict__ b,
    const float* __restrict__ ap, const unsigned* __restrict__ w7n, const unsigned* __restrict__ w7s,
    const unsigned* __restrict__ w8n, const unsigned* __restrict__ w8s, float* __restrict__ p4) {
    int h = blockIdx.x;   // 0..3
    int n = blockIdx.y;
    float a = ap[0];
    __shared__ unsigned q[9 * 4];      // [w][nz0,nz1,sg0,sg1]
    __shared__ signed char strit[9 * 128];
    __shared__ unsigned an[9 * 4], ag[9 * 4];
    int t = threadIdx.x;
    if (t < 18) {
        int w = t >> 1, half = t & 1;
        unsigned nz = 0, sg = 0;
        for (int j = 0; j < 32; ++j) {
            int ci = half * 32 + j;
            float v = p3[(n * 64 + ci) * 36 + h * 9 + w];
            float bnv = (v - mean[ci]) * rstd[ci] * g[ci] + b[ci];
            float pr = bnv < 0.f ? a * bnv : bnv;
            if (pr != 0.f) { nz |= 1u << j; if (pr < 0.f) sg |= 1u << j; }
        }
        q[w * 4 + half] = nz; q[w * 4 + 2 + half] = sg;
    }
    __syncthreads();
    // conv7 per (w, co): 9*128 = 1152 items
    for (int o = t; o < 1152; o += 256) {
        int w = o / 128, co = o % 128;
        int cnt = 0, neg = 0;
        for (int kw = 0; kw < 3; ++kw) {
            int wl = w + kw - 1;
            if (wl < 0 || wl >= 9) continue;
#pragma unroll
            for (int iw = 0; iw < 2; ++iw) {
                unsigned both = q[wl * 4 + iw] & w7n[(co * 3 + kw) * 2 + iw];
                cnt += __popc(both);
                neg += __popc((q[wl * 4 + 2 + iw] ^ w7s[(co * 3 + kw) * 2 + iw]) & both);
            }
        }
        int s = cnt - 2 * neg;
        strit[o] = (signed char)((s > 0) - (s < 0));
    }
    __syncthreads();
    if (t < 36) {
        int w = t >> 2, wi = t & 3;
        unsigned nz = 0, sg = 0;
        for (int j = 0; j < 32; ++j) {
            int tr = strit[w * 128 + wi * 32 + j];
            if (tr) { nz |= 1u << j; if (tr < 0) sg |= 1u << j; }
        }
        an[w * 4 + wi] = nz; ag[w * 4 + wi] = sg;
    }
    __syncthreads();
    // conv8 per (co, wo): 128*3 = 384 items
    for (int o = t; o < 384; o += 256) {
        int co = o / 3, wo = o % 3;
        int cnt = 0, neg = 0;
        for (int kw = 0; kw < 3; ++kw) {
            int wl = 3 * wo + kw;
#pragma unroll
            for (int iw = 0; iw < 4; ++iw) {
                unsigned both = an[wl * 4 + iw] & w8n[(co * 3 + kw) * 4 + iw];
                cnt += __popc(both);
                neg += __popc((ag[wl * 4 + iw] ^ w8s[(co * 3 + kw) * 4 + iw]) & both);
            }
        }
        p4[(n * 128 + co) * 12 + h * 3 + wo] = (float)(cnt - 2 * neg);
    }
}

// ---------------- stage 5: grid(4,512): one h-row per block ----------------
__global__ void stage5_kernel(const float* __restrict__ p4, const float* __restrict__ mean,
    const float* __restrict__ rstd, const float* __restrict__ g, const float* __restrict__ b,
    const float* __restrict__ ap, const unsigned* __restrict__ w9n, const unsigned* __restrict__ w9s,
    const unsigned* __restrict__ w10n, const unsigned* __restrict__ w10s, float* __restrict__ p5) {
    int h = blockIdx.x;   // 0..3
    int n = blockIdx.y;
    float a = ap[0];
    __shared__ unsigned q[3 * 8];      // [w][nz0..3, sg0..3]
    __shared__ signed char strit[3 * 256];
    __shared__ unsigned an[3 * 8], ag[3 * 8];
    int t = threadIdx.x;
    if (t < 12) {
        int w = t >> 2, wq = t & 3;
        unsigned nz = 0, sg = 0;
        for (int j = 0; j < 32; ++j) {
            int ci = wq * 32 + j;
            float v = p4[(n * 128 + ci) * 12 + h * 3 + w];
            float bnv = (v - mean[ci]) * rstd[ci] * g[ci] + b[ci];
            float pr = bnv < 0.f ? a * bnv : bnv;
            if (pr != 0.f) { nz |= 1u << j; if (pr < 0.f) sg |= 1u << j; }
        }
        q[w * 8 + wq] = nz; q[w * 8 + 4 + wq] = sg;
    }
    __syncthreads();
    // conv9 per (w, co): 3*256 = 768 items
    for (int o = t; o < 768; o += 256) {
        int w = o / 256, co = o % 256;
        int cnt = 0, neg = 0;
        for (int kw = 0; kw < 3; ++kw) {
            int wl = w + kw - 1;
            if (wl < 0 || wl >= 3) continue;
#pragma unroll
            for (int iw = 0; iw < 4; ++iw) {
                unsigned both = q[wl * 8 + iw] & w9n[(co * 3 + kw) * 4 + iw];
                cnt += __popc(both);
                neg += __popc((q[wl * 8 + 4 + iw] ^ w9s[(co * 3 + kw) * 4 + iw]) & both);
            }
        }
        int s = cnt - 2 * neg;
        strit[o] = (signed char)((s > 0) - (s < 0));
    }
    __syncthreads();
    if (t < 24) {
        int w = t >> 3, wi = t & 7;
        unsigned nz = 0, sg = 0;
        for (int j = 0; j < 32; ++j) {
            int tr = strit[w * 256 + wi * 32 + j];
            if (tr) { nz |= 1u << j; if (tr < 0) sg |= 1u << j; }
        }
        an[w * 8 + wi] = nz; ag[w * 8 + wi] = sg;
    }
    __syncthreads();
    // conv10 per co: 256 items
    if (t < 256) {
        int co = t;
        int cnt = 0, neg = 0;
        for (int kw = 0; kw < 3; ++kw) {
#pragma unroll
            for (int iw = 0; iw < 8; ++iw) {
                unsigned both = an[kw * 8 + iw] & w10n[(co * 3 + kw) * 8 + iw];
                cnt += __popc(both);
                neg += __popc((ag[kw * 8 + iw] ^ w10s[(co * 3 + kw) * 8 + iw]) & both);
            }
        }
        p5[n * 1024 + co * 4 + h] = (float)(cnt - 2 * neg);
    }
}

// ---------------- fc1: prelu(bn2d(p5)) @ sign(fc1).T, wave-per-output ----------------
__global__ void fc1_kernel(const float* __restrict__ p5, const float* __restrict__ mean,
                           const float* __restrict__ rstd, const float* __restrict__ g,
                           const float* __restrict__ b, const float* __restrict__ ap,
                           const float* __restrict__ sfc1, float* __restrict__ h1) {
    int n = blockIdx.x;
    float a = ap[0];
    __shared__ float hv[1024];
    int t = threadIdx.x;
    for (int idx = t; idx < 1024; idx += 256) {
        int c = idx >> 2;
        float v = p5[n * 1024 + idx];
        float bnv = (v - mean[c]) * rstd[c] * g[c] + b[c];
        hv[idx] = bnv < 0.f ? a * bnv : bnv;
    }
    __syncthreads();
    int wave = t >> 6, lane = t & 63;
    float hr[16];
#pragma unroll
    for (int m = 0; m < 16; ++m) hr[m] = hv[lane * 16 + m];
    for (int jj = 0; jj < 64; ++jj) {
        int j = wave * 64 + jj;
        const float4* wr = (const float4*)(sfc1 + (j << 10) + (lane << 4));
        double s = 0.0;
#pragma unroll
        for (int q4 = 0; q4 < 4; ++q4) {
            float4 wv = wr[q4];
            s += (double)(hr[q4 * 4 + 0] * wv.x);
            s += (double)(hr[q4 * 4 + 1] * wv.y);
            s += (double)(hr[q4 * 4 + 2] * wv.z);
            s += (double)(hr[q4 * 4 + 3] * wv.w);
        }
#pragma unroll
        for (int off = 32; off > 0; off >>= 1) s += __shfl_down(s, off, 64);
        if (lane == 0) h1[n * 256 + j] = (float)s;
    }
}

// ---------------- fc2 ----------------
__global__ void fc2_kernel(const float* __restrict__ h1, const float* __restrict__ mean,
                           const float* __restrict__ rstd, const float* __restrict__ g,
                           const float* __restrict__ b, const float* __restrict__ ap,
                           const float* __restrict__ sfc2, float* __restrict__ h2) {
    int n = blockIdx.x;
    float a = ap[0];
    __shared__ float sv[256];
    int t = threadIdx.x;
    if (t < 256) {
        float v = h1[n * 256 + t];
        float bnv = (v - mean[t]) * rstd[t] * g[t] + b[t];
        float pr = bnv < 0.f ? a * bnv : bnv;
        sv[t] = fsign(pr);
    }
    __syncthreads();
    if (t < 64) {
        float s = 0.f;
        for (int k = 0; k < 256; ++k) s += sv[k] * sfc2[t * 256 + k];
        h2[n * 64 + t] = s;
    }
}

// ---------------- fc3 ----------------
__global__ void fc3_kernel(const float* __restrict__ h2, const float* __restrict__ mean,
                           const float* __restrict__ rstd, const float* __restrict__ g,
                           const float* __restrict__ b, const float* __restrict__ ap,
                           const float* __restrict__ sfc3, float* __restrict__ out) {
    int n = blockIdx.x;
    float a = ap[0];
    __shared__ float sv[64];
    int t = threadIdx.x;
    if (t < 64) {
        float v = h2[n * 64 + t];
        float bnv = (v - mean[t]) * rstd[t] * g[t] + b[t];
        float pr = bnv < 0.f ? a * bnv : bnv;
        sv[t] = fsign(pr);
    }
    __syncthreads();
    if (t < 2) {
        float s = 0.f;
        for (int k = 0; k < 64; ++k) s += sv[k] * sfc3[t * 64 + k];
        out[n * 2 + t] = s;
    }
}

extern "C" void kernel_launch(void* const* d_in, const int* in_sizes, int n_in,
                              void* d_out, int out_size, void* d_ws, size_t ws_size,
                              hipStream_t stream) {
    const float* x = (const float*)d_in[0];
    // dict order: 0:x, 1-10:w1..w10, stage i: g=11+3(i-1), b=12+3(i-1), a=13+3(i-1)
    // 26:fc1, 27:fc2, 28:fc3, 29:g6, 30:b6, 31:g7, 32:b7, 33:a6, 34:a7
    const float* G[8] = {nullptr, (const float*)d_in[11], (const float*)d_in[14],
                         (const float*)d_in[17], (const float*)d_in[20], (const float*)d_in[23],
                         (const float*)d_in[29], (const float*)d_in[31]};
    const float* B[8] = {nullptr, (const float*)d_in[12], (const float*)d_in[15],
                         (const float*)d_in[18], (const float*)d_in[21], (const float*)d_in[24],
                         (const float*)d_in[30], (const float*)d_in[32]};
    const float* A[8] = {nullptr, (const float*)d_in[13], (const float*)d_in[16],
                         (const float*)d_in[19], (const float*)d_in[22], (const float*)d_in[25],
                         (const float*)d_in[33], (const float*)d_in[34]};

    float* ws = (float*)d_ws;
    size_t off = 0;
    const int fsz[3] = {262144, 16384, 128};
    float* fw[3];
    for (int i = 0; i < 3; ++i) { fw[i] = ws + off; off += (size_t)fsz[i]; }
    float* sfc1 = fw[0]; float* sfc2 = fw[1]; float* sfc3 = fw[2];
    float* wc = ws + off; off += 208;   // composite stage1 weights (integer-valued)

    const int psz[8] = {160, 160, 704, 1408, 768, 1536, 3072, 6144};
    unsigned* pn[8]; unsigned* pg[8];
    for (int i = 0; i < 8; ++i) {
        pn[i] = (unsigned*)(ws + off); off += (size_t)psz[i];
        pg[i] = (unsigned*)(ws + off); off += (size_t)psz[i];
    }

    float* p1 = ws + off; off += 16220160;   // 512*16*220*9
    float* p2 = ws + off; off += 6488064;    // 512*32*44*9
    float* p3 = ws + off; off += 1179648;    // 512*64*4*9
    float* p4 = ws + off; off += 786432;     // 512*128*4*3
    float* p5 = ws + off; off += 524288;     // 512*1024
    float* h1 = ws + off; off += 131072;     // 512*256
    float* h2 = ws + off; off += 32768;      // 512*64
    float* mean1 = ws + off; off += 16;  float* rstd1 = ws + off; off += 16;
    float* mean2 = ws + off; off += 32;  float* rstd2 = ws + off; off += 32;
    float* mean3 = ws + off; off += 64;  float* rstd3 = ws + off; off += 64;
    float* mean4 = ws + off; off += 128; float* rstd4 = ws + off; off += 128;
    float* mean5 = ws + off; off += 256; float* rstd5 = ws + off; off += 256;
    float* mean6 = ws + off; off += 256; float* rstd6 = ws + off; off += 256;
    float* mean7 = ws + off; off += 64;  float* rstd7 = ws + off; off += 64;
    if (off & 1) off += 1;  // 8B-align
    double* part = (double*)(ws + off); off += 2 * 16384;

    // 1. sign fc weights + build composite stage1 weights
    WPtrs wp;
    const int fsrc_idx[3] = {26, 27, 28};
    for (int i = 0; i < 3; ++i) {
        wp.src[i] = (const float*)d_in[fsrc_idx[i]];
        wp.dst[i] = fw[i];
        wp.n[i] = fsz[i];
    }
    hipLaunchKernelGGL(sign_weights_kernel, dim3(32, 3), dim3(256), 0, stream, wp);
    hipLaunchKernelGGL(build_wc_kernel, dim3(1), dim3(256), 0, stream,
                       (const float*)d_in[1], (const float*)d_in[2], wc);

    // 2. pack conv weights w3..w10
    PWall pa;
    const int cout_[8] = {32, 32, 64, 64, 128, 128, 256, 256};
    const int cin_[8]  = {16, 32, 32, 64, 64, 128, 128, 256};
    const int kk_[8]   = {5, 5, 11, 11, 3, 3, 3, 3};
    for (int i = 0; i < 8; ++i) {
        pa.l[i].src = (const float*)d_in[3 + i];
        pa.l[i].dnz = pn[i];
        pa.l[i].dsg = pg[i];
        pa.l[i].cout = cout_[i];
        pa.l[i].cin = cin_[i];
        pa.l[i].k = kk_[i];
        pa.l[i].nw = (cin_[i] + 31) / 32;
    }
    hipLaunchKernelGGL(pack_weights_kernel, dim3(4, 8), dim3(256), 0, stream, pa);

    // 3. stage1 (composite 13-tap) -> p1, stats
    hipLaunchKernelGGL(stage1_kernel, dim3(8, 512), dim3(256), 0, stream, x, wc, p1);
    hipLaunchKernelGGL(stats_rows, dim3(16, 64), dim3(256), 0, stream, p1, 16, 512, 1980, 64, part);
    hipLaunchKernelGGL(stats_final, dim3(1), dim3(256), 0, stream, part, 16, 64, (long)512 * 1980, mean1, rstd1);

    // 4. stage2 -> p2, stats
    hipLaunchKernelGGL(stage2_kernel, dim3(11, 512), dim3(256), 0, stream, p1, mean1, rstd1,
                       G[1], B[1], A[1], pn[0], pg[0], pn[1], pg[1], p2);
    hipLaunchKernelGGL(stats_rows, dim3(32, 64), dim3(256), 0, stream, p2, 32, 512, 396, 64, part);
    hipLaunchKernelGGL(stats_final, dim3(1), dim3(256), 0, stream, part, 32, 64, (long)512 * 396, mean2, rstd2);

    // 5. stage3 -> p3, stats
    hipLaunchKernelGGL(stage3_kernel, dim3(4, 512), dim3(256), 0, stream, p2, mean2, rstd2,
                       G[2], B[2], A[2], pn[2], pg[2], pn[3], pg[3], p3);
    hipLaunchKernelGGL(stats_rows, dim3(64, 16), dim3(256), 0, stream, p3, 64, 512, 36, 16, part);
    hipLaunchKernelGGL(stats_final, dim3(1), dim3(256), 0, stream, part, 64, 16, (long)512 * 36, mean3, rstd3);

    // 6. stage4 -> p4, stats
    hipLaunchKernelGGL(stage4_kernel, dim3(4, 512), dim3(256), 0, stream, p3, mean3, rstd3,
                       G[3], B[3], A[3], pn[4], pg[4], pn[5], pg[5], p4);
    hipLaunchKernelGGL(stats_rows, dim3(128, 16), dim3(256), 0, stream, p4, 128, 512, 12, 16, part);
    hipLaunchKernelGGL(stats_final, dim3(1), dim3(256), 0, stream, part, 128, 16, (long)512 * 12, mean4, rstd4);

    // 7. stage5 -> p5, stats
    hipLaunchKernelGGL(stage5_kernel, dim3(4, 512), dim3(256), 0, stream, p4, mean4, rstd4,
                       G[4], B[4], A[4], pn[6], pg[6], pn[7], pg[7], p5);
    hipLaunchKernelGGL(stats_rows, dim3(256, 8), dim3(256), 0, stream, p5, 256, 512, 4, 8, part);
    hipLaunchKernelGGL(stats_final, dim3(1), dim3(256), 0, stream, part, 256, 8, (long)512 * 4, mean5, rstd5);

    // 8. fc1 -> h1, stats
    hipLaunchKernelGGL(fc1_kernel, dim3(512), dim3(256), 0, stream, p5, mean5, rstd5,
                       G[5], B[5], A[5], sfc1, h1);
    hipLaunchKernelGGL(stats_bn1d, dim3(256), dim3(64), 0, stream, h1, 256, 512, mean6, rstd6);

    // 9. fc2 -> h2, stats
    hipLaunchKernelGGL(fc2_kernel, dim3(512), dim3(256), 0, stream, h1, mean6, rstd6,
                       G[6], B[6], A[6], sfc2, h2);
    hipLaunchKernelGGL(stats_bn1d, dim3(64), dim3(64), 0, stream, h2, 64, 512, mean7, rstd7);

    // 10. fc3 -> d_out
    hipLaunchKernelGGL(fc3_kernel, dim3(512), dim3(256), 0, stream, h2, mean7, rstd7,
                       G[7], B[7], A[7], sfc3, (float*)d_out);
}